// Round 10
// baseline (473.724 us; speedup 1.0000x reference)
//
#include <hip/hip_runtime.h>

#define N_NODES 50000
#define N_EDGES 800000
#define IN_CH   128
#define OUT_CH  32
#define HEADS   10
#define HC      320           // HEADS*OUT_CH
#define N_GRAPHS 512
#define NEG_SLOPE 0.2f
#define NBLK_SCAN 196         // ceil(50000/256)

typedef __attribute__((ext_vector_type(8))) short bf16x8;   // 8 bf16 in 4 VGPRs
typedef __attribute__((ext_vector_type(4))) float f32x4;

// ---- order-preserving float<->uint map for atomicMax-based segment_max ----
__device__ __forceinline__ unsigned fmap(float f) {
  unsigned u = __float_as_uint(f);
  return (u & 0x80000000u) ? ~u : (u | 0x80000000u);
}
__device__ __forceinline__ float funmap(unsigned u) {
  u = (u & 0x80000000u) ? (u ^ 0x80000000u) : ~u;
  return __uint_as_float(u);
}
__device__ __forceinline__ float leaky(float a) {
  return a > 0.f ? a : NEG_SLOPE * a;
}
// ---- bf16 helpers (RNE) + hi/lo split store ----
__device__ __forceinline__ unsigned short f2bf(float f) {
  unsigned u = __float_as_uint(f);
  return (unsigned short)((u + 0x7FFFu + ((u >> 16) & 1u)) >> 16);
}
__device__ __forceinline__ float bf2f(unsigned short b) {
  return __uint_as_float(((unsigned)b) << 16);
}
__device__ __forceinline__ void store_split(unsigned short* __restrict__ ph,
                                            unsigned short* __restrict__ pl,
                                            size_t idx, float v) {
  unsigned short h = f2bf(v);
  ph[idx] = h;
  pl[idx] = f2bf(v - bf2f(h));
}

// ============================ CSR construction =============================
__global__ __launch_bounds__(256) void hist_k(const int* __restrict__ ei,
                                              int* __restrict__ deg) {
  int e = blockIdx.x * 256 + threadIdx.x;
  if (e < N_EDGES) atomicAdd(&deg[ei[N_EDGES + e]], 1);
}

__global__ __launch_bounds__(256) void scan_blk(const int* __restrict__ deg,
                                                int* __restrict__ roff,
                                                int* __restrict__ bsum) {
  __shared__ int s[256];
  int i = blockIdx.x * 256 + threadIdx.x;
  int v = (i < N_NODES) ? deg[i] : 0;
  s[threadIdx.x] = v;
  __syncthreads();
  #pragma unroll
  for (int o = 1; o < 256; o <<= 1) {
    int t = (threadIdx.x >= o) ? s[threadIdx.x - o] : 0;
    __syncthreads();
    s[threadIdx.x] += t;
    __syncthreads();
  }
  if (i < N_NODES) roff[i] = s[threadIdx.x] - v;   // exclusive
  if (threadIdx.x == 255) bsum[blockIdx.x] = s[255];
}

__global__ __launch_bounds__(256) void scan_top(int* __restrict__ bsum) {
  __shared__ int s[256];
  int i = threadIdx.x;
  int v = (i < NBLK_SCAN) ? bsum[i] : 0;
  s[i] = v;
  __syncthreads();
  #pragma unroll
  for (int o = 1; o < 256; o <<= 1) {
    int t = (i >= o) ? s[i - o] : 0;
    __syncthreads();
    s[i] += t;
    __syncthreads();
  }
  if (i < NBLK_SCAN) bsum[i] = s[i] - v;           // exclusive
}

__global__ __launch_bounds__(256) void scan_add(int* __restrict__ roff,
                                                const int* __restrict__ bsum) {
  int i = blockIdx.x * 256 + threadIdx.x;
  if (i < N_NODES) roff[i] += bsum[blockIdx.x];
  if (i == 0) roff[N_NODES] = N_EDGES;
}

__global__ __launch_bounds__(256) void scatter_k(const int* __restrict__ ei,
                                                 const int* __restrict__ roff,
                                                 int* __restrict__ cursor,
                                                 int* __restrict__ ssrc) {
  int e = blockIdx.x * 256 + threadIdx.x;
  if (e >= N_EDGES) return;
  int dst = ei[N_EDGES + e];
  int pos = roff[dst] + atomicAdd(&cursor[dst], 1);
  ssrc[pos] = ei[e];
}

// =================== bf16 hi/lo conversions for MFMA GEMMs =================
__global__ __launch_bounds__(256) void conv_x(const float* __restrict__ X,
                                              unsigned short* __restrict__ Xh,
                                              unsigned short* __restrict__ Xl) {
  int i = blockIdx.x * 256 + threadIdx.x;          // float4 index
  if (i >= N_NODES * IN_CH / 4) return;
  float4 v = reinterpret_cast<const float4*>(X)[i];
  ushort4 h, l;
  h.x = f2bf(v.x); l.x = f2bf(v.x - bf2f(h.x));
  h.y = f2bf(v.y); l.y = f2bf(v.y - bf2f(h.y));
  h.z = f2bf(v.z); l.z = f2bf(v.z - bf2f(h.z));
  h.w = f2bf(v.w); l.w = f2bf(v.w - bf2f(h.w));
  reinterpret_cast<ushort4*>(Xh)[i] = h;
  reinterpret_cast<ushort4*>(Xl)[i] = l;
}

// W1[128][320] -> W1T[320][128] hi/lo ; W2[320][32] -> W2T[32][320] hi/lo
__global__ __launch_bounds__(256) void conv_w(const float* __restrict__ W1,
                                              const float* __restrict__ W2,
                                              unsigned short* __restrict__ W1hT,
                                              unsigned short* __restrict__ W1lT,
                                              unsigned short* __restrict__ W2hT,
                                              unsigned short* __restrict__ W2lT) {
  int i = blockIdx.x * 256 + threadIdx.x;
  if (i < IN_CH * HC) {                 // i = n*128 + k
    int n = i >> 7, k = i & 127;
    float v = W1[(size_t)k * HC + n];
    unsigned short h = f2bf(v);
    W1hT[i] = h; W1lT[i] = f2bf(v - bf2f(h));
  } else {
    int j = i - IN_CH * HC;
    if (j < OUT_CH * HC) {              // j = c*320 + k
      int c = j / HC, k = j - c * HC;
      float v = W2[(size_t)k * OUT_CH + c];
      unsigned short h = f2bf(v);
      W2hT[j] = h; W2lT[j] = f2bf(v - bf2f(h));
    }
  }
}

// ======== GEMM1 via MFMA split-bf16: h1[N,320] = X[N,128] @ W1[128,320] ====
// wave -> one 16x16 C tile; 4 k-steps x 3 products; frags direct from global.
// A frag: A[r][k], r=lane&15, k=(lane>>4)*8+j (row-major X, contiguous 8).
// B frag: B[k][c], c=lane&15 -> row of W^T, contiguous 8 k.
// C/D:    col=lane&15, row=(lane>>4)*4+reg   [verified m89]
__global__ __launch_bounds__(256) void gemm1_mfma(const unsigned short* __restrict__ Xh,
                                                  const unsigned short* __restrict__ Xl,
                                                  const unsigned short* __restrict__ WhT,
                                                  const unsigned short* __restrict__ WlT,
                                                  float* __restrict__ H) {
  const int wave = threadIdx.x >> 6;
  const int lane = threadIdx.x & 63;
  const int col0 = blockIdx.x * 16;                  // 20 col tiles
  const int row0 = blockIdx.y * 64 + wave * 16;
  const int r = lane & 15;
  const int kg = lane >> 4;                          // 0..3
  int arow = row0 + r; if (arow >= N_NODES) arow = N_NODES - 1;
  const unsigned short* xh = Xh + (size_t)arow * IN_CH + kg * 8;
  const unsigned short* xl = Xl + (size_t)arow * IN_CH + kg * 8;
  const unsigned short* wh = WhT + (size_t)(col0 + r) * IN_CH + kg * 8;
  const unsigned short* wl = WlT + (size_t)(col0 + r) * IN_CH + kg * 8;
  f32x4 acc = {0.f, 0.f, 0.f, 0.f};
  #pragma unroll
  for (int k0 = 0; k0 < IN_CH; k0 += 32) {
    bf16x8 ah = *reinterpret_cast<const bf16x8*>(xh + k0);
    bf16x8 al = *reinterpret_cast<const bf16x8*>(xl + k0);
    bf16x8 bh = *reinterpret_cast<const bf16x8*>(wh + k0);
    bf16x8 bl = *reinterpret_cast<const bf16x8*>(wl + k0);
    acc = __builtin_amdgcn_mfma_f32_16x16x32_bf16(ah, bh, acc, 0, 0, 0);
    acc = __builtin_amdgcn_mfma_f32_16x16x32_bf16(ah, bl, acc, 0, 0, 0);
    acc = __builtin_amdgcn_mfma_f32_16x16x32_bf16(al, bh, acc, 0, 0, 0);
  }
  const int crow0 = row0 + kg * 4;
  const int ccol = col0 + r;
  #pragma unroll
  for (int t = 0; t < 4; t++) {
    int rr = crow0 + t;
    if (rr < N_NODES) H[(size_t)rr * HC + ccol] = acc[t];
  }
}

// ======== GEMM2 via MFMA split-bf16: h2[N,32] = act[N,320] @ W2[320,32] ====
__global__ __launch_bounds__(256) void gemm2_mfma(const unsigned short* __restrict__ Ah,
                                                  const unsigned short* __restrict__ Al,
                                                  const unsigned short* __restrict__ WhT,
                                                  const unsigned short* __restrict__ WlT,
                                                  float* __restrict__ H) {
  const int wave = threadIdx.x >> 6;
  const int lane = threadIdx.x & 63;
  const int col0 = blockIdx.x * 16;                  // 2 col tiles
  const int row0 = blockIdx.y * 64 + wave * 16;
  const int r = lane & 15;
  const int kg = lane >> 4;
  int arow = row0 + r; if (arow >= N_NODES) arow = N_NODES - 1;
  const unsigned short* ah_p = Ah + (size_t)arow * HC + kg * 8;
  const unsigned short* al_p = Al + (size_t)arow * HC + kg * 8;
  const unsigned short* wh = WhT + (size_t)(col0 + r) * HC + kg * 8;
  const unsigned short* wl = WlT + (size_t)(col0 + r) * HC + kg * 8;
  f32x4 acc = {0.f, 0.f, 0.f, 0.f};
  #pragma unroll
  for (int k0 = 0; k0 < HC; k0 += 32) {
    bf16x8 ah = *reinterpret_cast<const bf16x8*>(ah_p + k0);
    bf16x8 al = *reinterpret_cast<const bf16x8*>(al_p + k0);
    bf16x8 bh = *reinterpret_cast<const bf16x8*>(wh + k0);
    bf16x8 bl = *reinterpret_cast<const bf16x8*>(wl + k0);
    acc = __builtin_amdgcn_mfma_f32_16x16x32_bf16(ah, bh, acc, 0, 0, 0);
    acc = __builtin_amdgcn_mfma_f32_16x16x32_bf16(ah, bl, acc, 0, 0, 0);
    acc = __builtin_amdgcn_mfma_f32_16x16x32_bf16(al, bh, acc, 0, 0, 0);
  }
  const int crow0 = row0 + kg * 4;
  const int ccol = col0 + r;
  #pragma unroll
  for (int t = 0; t < 4; t++) {
    int rr = crow0 + t;
    if (rr < N_NODES) H[(size_t)rr * OUT_CH + ccol] = acc[t];
  }
}

// -------- e_src/e_dst per (node, head): dot(h1[n,h,:], a_src[h,:]) ---------
__global__ __launch_bounds__(256) void edot1(const float* __restrict__ h1,
                                             const float* __restrict__ a_src,
                                             const float* __restrict__ a_dst,
                                             float* __restrict__ es,
                                             float* __restrict__ ed) {
  int idx = blockIdx.x * 256 + threadIdx.x;
  if (idx >= N_NODES * HEADS) return;
  int n = idx / HEADS, h = idx - n * HEADS;
  const float4* hp = reinterpret_cast<const float4*>(h1 + (size_t)n * HC + h * OUT_CH);
  const float4* ap = reinterpret_cast<const float4*>(a_src + h * OUT_CH);
  const float4* bp = reinterpret_cast<const float4*>(a_dst + h * OUT_CH);
  float s = 0.f, d = 0.f;
  #pragma unroll
  for (int q = 0; q < 8; q++) {
    float4 hv = hp[q], av = ap[q], dv = bp[q];
    s += hv.x * av.x + hv.y * av.y + hv.z * av.z + hv.w * av.w;
    d += hv.x * dv.x + hv.y * dv.y + hv.z * dv.z + hv.w * dv.w;
  }
  es[idx] = s; ed[idx] = d;
}

// ------ layer-1 aggregation: one wave per dst node, wave-coop softmax ------
// lane covers cols t = lane + 64q (q=0..4); head of (lane,q) = 2q + (lane>>5)
// epilogue writes act as bf16 hi/lo splits for the MFMA gemm2.
__global__ __launch_bounds__(256) void agg1(const int* __restrict__ roff,
                                            const int* __restrict__ ssrc,
                                            const float* __restrict__ es,
                                            const float* __restrict__ ed,
                                            const float* __restrict__ h1,
                                            const float* __restrict__ b1,
                                            unsigned short* __restrict__ acth,
                                            unsigned short* __restrict__ actl) {
  __shared__ float lds[4][64][11];   // [wave][edge][0..9]=ex, [10]=src bits
  const int n = (blockIdx.x * 256 + threadIdx.x) >> 6;
  if (n >= N_NODES) return;
  const int wslot = threadIdx.x >> 6;
  const int lane = threadIdx.x & 63;
  const int hb = lane >> 5;                 // 0 or 1
  const int beg = roff[n];
  const int deg = roff[n + 1] - beg;

  if (deg == 0) {
    #pragma unroll
    for (int q = 0; q < 5; q++) {
      float v = b1[lane + 64 * q];
      v = v > 0.f ? v : expm1f(v);
      store_split(acth, actl, (size_t)n * HC + lane + 64 * q, v);
    }
    return;
  }

  float acc[5] = {};

  if (deg <= 64) {
    // ---- phase 1: lane e owns edge e; compute 10 alphas in registers ----
    const int active = (lane < deg);
    const int src = ssrc[beg + (active ? lane : 0)];
    float a[10];
    #pragma unroll
    for (int p = 0; p < 5; p++) {
      float2 edp = *reinterpret_cast<const float2*>(ed + n * 10 + 2 * p);
      float2 esp = *reinterpret_cast<const float2*>(es + src * 10 + 2 * p);
      a[2 * p]     = active ? leaky(esp.x + edp.x) : -1e30f;
      a[2 * p + 1] = active ? leaky(esp.y + edp.y) : -1e30f;
    }
    // per-head wave max
    float m[10];
    #pragma unroll
    for (int h = 0; h < 10; h++) m[h] = a[h];
    #pragma unroll
    for (int o = 1; o < 64; o <<= 1)
      #pragma unroll
      for (int h = 0; h < 10; h++) m[h] = fmaxf(m[h], __shfl_xor(m[h], o));
    // exp, park in LDS; per-head wave denom
    float d[10];
    #pragma unroll
    for (int h = 0; h < 10; h++) {
      float ex = expf(a[h] - m[h]);        // 0 for inactive lanes
      lds[wslot][lane][h] = ex;
      d[h] = ex;
    }
    lds[wslot][lane][10] = __int_as_float(src);
    #pragma unroll
    for (int o = 1; o < 64; o <<= 1)
      #pragma unroll
      for (int h = 0; h < 10; h++) d[h] += __shfl_xor(d[h], o);

    // ---- phase 2: gather h1 rows weighted by LDS-broadcast coefs ----
    int j = 0;
    for (; j + 4 <= deg; j += 4) {
      int s0 = __float_as_int(lds[wslot][j + 0][10]);
      int s1 = __float_as_int(lds[wslot][j + 1][10]);
      int s2 = __float_as_int(lds[wslot][j + 2][10]);
      int s3 = __float_as_int(lds[wslot][j + 3][10]);
      const float* __restrict__ r0 = h1 + (size_t)s0 * HC + lane;
      const float* __restrict__ r1 = h1 + (size_t)s1 * HC + lane;
      const float* __restrict__ r2 = h1 + (size_t)s2 * HC + lane;
      const float* __restrict__ r3 = h1 + (size_t)s3 * HC + lane;
      float v0[5], v1[5], v2[5], v3[5];
      #pragma unroll
      for (int q = 0; q < 5; q++) v0[q] = r0[64 * q];
      #pragma unroll
      for (int q = 0; q < 5; q++) v1[q] = r1[64 * q];
      #pragma unroll
      for (int q = 0; q < 5; q++) v2[q] = r2[64 * q];
      #pragma unroll
      for (int q = 0; q < 5; q++) v3[q] = r3[64 * q];
      #pragma unroll
      for (int q = 0; q < 5; q++) {
        acc[q] = fmaf(v0[q], lds[wslot][j + 0][2 * q + hb], acc[q]);
        acc[q] = fmaf(v1[q], lds[wslot][j + 1][2 * q + hb], acc[q]);
        acc[q] = fmaf(v2[q], lds[wslot][j + 2][2 * q + hb], acc[q]);
        acc[q] = fmaf(v3[q], lds[wslot][j + 3][2 * q + hb], acc[q]);
      }
    }
    for (; j < deg; j++) {
      int sj = __float_as_int(lds[wslot][j][10]);
      const float* __restrict__ hrow = h1 + (size_t)sj * HC + lane;
      #pragma unroll
      for (int q = 0; q < 5; q++)
        acc[q] = fmaf(hrow[64 * q], lds[wslot][j][2 * q + hb], acc[q]);
    }
    #pragma unroll
    for (int q = 0; q < 5; q++) {
      float v = acc[q] / (d[2 * q + hb] + 1e-16f) + b1[lane + 64 * q];
      v = v > 0.f ? v : expm1f(v);
      store_split(acth, actl, (size_t)n * HC + lane + 64 * q, v);
    }
  } else {
    // ---- slow fallback (deg > 64): per-lane redundant 2-pass ----
    float edv[5], m2[5];
    #pragma unroll
    for (int q = 0; q < 5; q++) { edv[q] = ed[n * 10 + 2 * q + hb]; m2[q] = -1e30f; }
    for (int j = beg; j < beg + deg; j++) {
      int src = ssrc[j];
      #pragma unroll
      for (int q = 0; q < 5; q++)
        m2[q] = fmaxf(m2[q], leaky(es[src * 10 + 2 * q + hb] + edv[q]));
    }
    float d2[5] = {};
    for (int j = beg; j < beg + deg; j++) {
      int src = ssrc[j];
      const float* hrow = h1 + (size_t)src * HC + lane;
      #pragma unroll
      for (int q = 0; q < 5; q++) {
        float ex = expf(leaky(es[src * 10 + 2 * q + hb] + edv[q]) - m2[q]);
        acc[q] = fmaf(hrow[64 * q], ex, acc[q]);
        d2[q] += ex;
      }
    }
    #pragma unroll
    for (int q = 0; q < 5; q++) {
      float v = acc[q] / (d2[q] + 1e-16f) + b1[lane + 64 * q];
      v = v > 0.f ? v : expm1f(v);
      store_split(acth, actl, (size_t)n * HC + lane + 64 * q, v);
    }
  }
}

// ---------------- e_src2/e_dst2 per node (H=1) -----------------------------
__global__ __launch_bounds__(256) void edot2(const float* __restrict__ h2,
                                             const float* __restrict__ a_src,
                                             const float* __restrict__ a_dst,
                                             float* __restrict__ es,
                                             float* __restrict__ ed) {
  int n = blockIdx.x * 256 + threadIdx.x;
  if (n >= N_NODES) return;
  const float4* hp = reinterpret_cast<const float4*>(h2 + (size_t)n * OUT_CH);
  const float4* ap = reinterpret_cast<const float4*>(a_src);
  const float4* bp = reinterpret_cast<const float4*>(a_dst);
  float s = 0.f, d = 0.f;
  #pragma unroll
  for (int q = 0; q < 8; q++) {
    float4 hv = hp[q], av = ap[q], dv = bp[q];
    s += hv.x * av.x + hv.y * av.y + hv.z * av.z + hv.w * av.w;
    d += hv.x * dv.x + hv.y * dv.y + hv.z * dv.z + hv.w * dv.w;
  }
  es[n] = s; ed[n] = d;
}

// ------ layer-2 aggregation: one wave per node, unrolled, fused pool -------
__global__ __launch_bounds__(256) void agg2(const int* __restrict__ roff,
                                            const int* __restrict__ ssrc,
                                            const float* __restrict__ es,
                                            const float* __restrict__ ed,
                                            const float* __restrict__ h2,
                                            const float* __restrict__ b2,
                                            const int* __restrict__ batch,
                                            unsigned* __restrict__ pooled) {
  __shared__ float lds[4][64][2];    // [wave][edge][0]=ex, [1]=src bits
  const int n = (blockIdx.x * 256 + threadIdx.x) >> 6;
  if (n >= N_NODES) return;
  const int wslot = threadIdx.x >> 6;
  const int lane = threadIdx.x & 63;
  const int c = lane & 31;
  const int hb = lane >> 5;
  const int beg = roff[n];
  const int deg = roff[n + 1] - beg;
  const int g = batch[n];

  if (deg == 0) {
    if (lane < 32) {
      float v = b2[c];
      v = v > 0.f ? v : expm1f(v);
      atomicMax(&pooled[g * OUT_CH + c], fmap(v));
    }
    return;
  }

  float acc = 0.f, dtot;

  if (deg <= 64) {
    const int active = (lane < deg);
    const int src = ssrc[beg + (active ? lane : 0)];
    const float edv = ed[n];
    float a = active ? leaky(es[src] + edv) : -1e30f;
    float m = a;
    #pragma unroll
    for (int o = 1; o < 64; o <<= 1) m = fmaxf(m, __shfl_xor(m, o));
    float ex = expf(a - m);
    float d = ex;
    #pragma unroll
    for (int o = 1; o < 64; o <<= 1) d += __shfl_xor(d, o);
    dtot = d;
    lds[wslot][lane][0] = ex;
    lds[wslot][lane][1] = __int_as_float(src);
    int j = hb;
    for (; j + 6 < deg; j += 8) {
      int s0 = __float_as_int(lds[wslot][j + 0][1]);
      int s1 = __float_as_int(lds[wslot][j + 2][1]);
      int s2 = __float_as_int(lds[wslot][j + 4][1]);
      int s3 = __float_as_int(lds[wslot][j + 6][1]);
      float c0 = lds[wslot][j + 0][0];
      float c1 = lds[wslot][j + 2][0];
      float c2 = lds[wslot][j + 4][0];
      float c3 = lds[wslot][j + 6][0];
      float v0 = h2[(size_t)s0 * OUT_CH + c];
      float v1 = h2[(size_t)s1 * OUT_CH + c];
      float v2 = h2[(size_t)s2 * OUT_CH + c];
      float v3 = h2[(size_t)s3 * OUT_CH + c];
      acc = fmaf(v0, c0, acc);
      acc = fmaf(v1, c1, acc);
      acc = fmaf(v2, c2, acc);
      acc = fmaf(v3, c3, acc);
    }
    for (; j < deg; j += 2) {
      int sj = __float_as_int(lds[wslot][j][1]);
      acc = fmaf(h2[(size_t)sj * OUT_CH + c], lds[wslot][j][0], acc);
    }
  } else {
    const float edv = ed[n];
    float m = -1e30f;
    for (int j = beg; j < beg + deg; j++)
      m = fmaxf(m, leaky(es[ssrc[j]] + edv));
    float d = 0.f;
    for (int j = beg + hb; j < beg + deg; j += 2) {
      int src = ssrc[j];
      float ex = expf(leaky(es[src] + edv) - m);
      acc = fmaf(h2[(size_t)src * OUT_CH + c], ex, acc);
      d += ex;
    }
    d += __shfl_xor(d, 32);
    dtot = d;
  }

  acc += __shfl_xor(acc, 32);
  if (lane < 32) {
    float v = acc / (dtot + 1e-16f) + b2[c];
    v = v > 0.f ? v : expm1f(v);
    atomicMax(&pooled[g * OUT_CH + c], fmap(v));
  }
}

// -------- final: out[g,c] = relu(pooled[g,:] @ fc_w[:,c] + fc_b[c]) --------
__global__ __launch_bounds__(256) void final_k(const unsigned* __restrict__ pooled,
                                               const float* __restrict__ fc_w,
                                               const float* __restrict__ fc_b,
                                               float* __restrict__ out) {
  int idx = blockIdx.x * 256 + threadIdx.x;
  if (idx >= N_GRAPHS * OUT_CH) return;
  int g = idx >> 5, c = idx & 31;
  float s = fc_b[c];
  #pragma unroll
  for (int k = 0; k < OUT_CH; k++) {
    unsigned u = pooled[g * OUT_CH + k];
    float p = (u == 0u) ? 0.f : funmap(u);
    s += p * fc_w[k * OUT_CH + c];
  }
  out[idx] = s > 0.f ? s : 0.f;
}

extern "C" void kernel_launch(void* const* d_in, const int* in_sizes, int n_in,
                              void* d_out, int out_size, void* d_ws, size_t ws_size,
                              hipStream_t stream) {
  const float* x      = (const float*)d_in[0];
  const int*   ei     = (const int*)d_in[1];
  const int*   batch  = (const int*)d_in[2];
  const float* W1     = (const float*)d_in[4];
  const float* a_src1 = (const float*)d_in[5];
  const float* a_dst1 = (const float*)d_in[6];
  const float* b1     = (const float*)d_in[7];
  const float* W2     = (const float*)d_in[8];
  const float* a_src2 = (const float*)d_in[9];
  const float* a_dst2 = (const float*)d_in[10];
  const float* b2     = (const float*)d_in[11];
  const float* fc_w   = (const float*)d_in[12];
  const float* fc_b   = (const float*)d_in[13];
  float* out = (float*)d_out;

  // ---- workspace layout (<= 136 MB, phase-aliased) ----
  // A [0,64M):   h1 f32 (gemm1->agg1); h2 f32 reuses head after agg1
  // B [64M,128M): phase1 Xh|Xl (25.6M); phase2 act_h|act_l (64M)
  // S [128M,136M): CSR + es/ed + pooled; W-splits alias dead deg/cursor
  char* ws = (char*)d_ws;
  float* h1   = (float*)(ws);
  float* h2   = (float*)(ws);                               // after agg1
  unsigned short* Xh   = (unsigned short*)(ws + 64000000);  // 12.8 MB
  unsigned short* Xl   = (unsigned short*)(ws + 76800000);  // 12.8 MB
  unsigned short* acth = (unsigned short*)(ws + 64000000);  // 32 MB (after gemm1)
  unsigned short* actl = (unsigned short*)(ws + 96000000);  // 32 MB
  char*  S    = ws + 128000000;
  int*   ssrc   = (int*)(S);                  // 3.2 MB
  int*   roff   = (int*)(S + 3200000);        // 200,004 B
  int*   deg    = (int*)(S + 3400064);        // 200,000 B (dead after scan)
  int*   cursor = (int*)(S + 3600064);        // 200,000 B (dead after scatter)
  unsigned short* W1hT = (unsigned short*)(S + 3400064);            // 81,920 B
  unsigned short* W1lT = (unsigned short*)(S + 3400064 + 81920);    // 81,920 B
  unsigned short* W2hT = (unsigned short*)(S + 3400064 + 163840);   // 20,480 B
  unsigned short* W2lT = (unsigned short*)(S + 3400064 + 184320);   // 20,480 B
  float* es1    = (float*)(S + 3800064);      // 2 MB
  float* ed1    = (float*)(S + 5800064);      // 2 MB
  int*   bsum   = (int*)(S + 7800064);        // 784 B
  unsigned* pooled = (unsigned*)(S + 7801600);// 64 KB
  float* es2 = es1; float* ed2 = ed1;         // dead after agg1

  // ---- CSR build ----
  hipMemsetAsync(deg, 0, (size_t)N_NODES * 4, stream);
  hipMemsetAsync(cursor, 0, (size_t)N_NODES * 4, stream);
  hist_k   <<<(N_EDGES + 255) / 256, 256, 0, stream>>>(ei, deg);
  scan_blk <<<NBLK_SCAN, 256, 0, stream>>>(deg, roff, bsum);
  scan_top <<<1, 256, 0, stream>>>(bsum);
  scan_add <<<NBLK_SCAN, 256, 0, stream>>>(roff, bsum);
  scatter_k<<<(N_EDGES + 255) / 256, 256, 0, stream>>>(ei, roff, cursor, ssrc);

  // ---- bf16 splits (conv_w AFTER scatter: aliases deg/cursor) ----
  conv_x<<<(N_NODES * IN_CH / 4 + 255) / 256, 256, 0, stream>>>(x, Xh, Xl);
  conv_w<<<(IN_CH * HC + OUT_CH * HC + 255) / 256, 256, 0, stream>>>(
      W1, W2, W1hT, W1lT, W2hT, W2lT);

  // ---- layer 1 ----
  gemm1_mfma<<<dim3(HC / 16, (N_NODES + 63) / 64), 256, 0, stream>>>(
      Xh, Xl, W1hT, W1lT, h1);
  edot1<<<(N_NODES * HEADS + 255) / 256, 256, 0, stream>>>(h1, a_src1, a_dst1, es1, ed1);
  agg1 <<<(N_NODES * 64 + 255) / 256, 256, 0, stream>>>(roff, ssrc, es1, ed1, h1, b1,
                                                        acth, actl);

  // ---- layer 2 ----
  hipMemsetAsync(pooled, 0, (size_t)N_GRAPHS * OUT_CH * 4, stream);
  gemm2_mfma<<<dim3(OUT_CH / 16, (N_NODES + 63) / 64), 256, 0, stream>>>(
      acth, actl, W2hT, W2lT, h2);
  edot2<<<(N_NODES + 255) / 256, 256, 0, stream>>>(h2, a_src2, a_dst2, es2, ed2);
  agg2 <<<(N_NODES * 64 + 255) / 256, 256, 0, stream>>>(roff, ssrc, es2, ed2, h2, b2,
                                                        batch, pooled);
  final_k<<<(N_GRAPHS * OUT_CH + 255) / 256, 256, 0, stream>>>(pooled, fc_w, fc_b, out);
}

// Round 11
// 410.928 us; speedup vs baseline: 1.1528x; 1.1528x over previous
//
#include <hip/hip_runtime.h>

#define N_NODES 50000
#define N_EDGES 800000
#define IN_CH   128
#define OUT_CH  32
#define HEADS   10
#define HC      320           // HEADS*OUT_CH
#define N_GRAPHS 512
#define NEG_SLOPE 0.2f
#define NBLK_SCAN 196         // ceil(50000/256)

typedef __attribute__((ext_vector_type(8))) short bf16x8;   // 8 bf16 in 4 VGPRs
typedef __attribute__((ext_vector_type(4))) float f32x4;

// ---- order-preserving float<->uint map for atomicMax-based segment_max ----
__device__ __forceinline__ unsigned fmap(float f) {
  unsigned u = __float_as_uint(f);
  return (u & 0x80000000u) ? ~u : (u | 0x80000000u);
}
__device__ __forceinline__ float funmap(unsigned u) {
  u = (u & 0x80000000u) ? (u ^ 0x80000000u) : ~u;
  return __uint_as_float(u);
}
__device__ __forceinline__ float leaky(float a) {
  return a > 0.f ? a : NEG_SLOPE * a;
}
// ---- bf16 helpers (RNE) + hi/lo split store ----
__device__ __forceinline__ unsigned short f2bf(float f) {
  unsigned u = __float_as_uint(f);
  return (unsigned short)((u + 0x7FFFu + ((u >> 16) & 1u)) >> 16);
}
__device__ __forceinline__ float bf2f(unsigned short b) {
  return __uint_as_float(((unsigned)b) << 16);
}
// packed-pair unpack: uint holds bf16 c=2i (low16) and c=2i+1 (high16)
__device__ __forceinline__ float bflo(unsigned u) { return __uint_as_float(u << 16); }
__device__ __forceinline__ float bfhi(unsigned u) { return __uint_as_float(u & 0xFFFF0000u); }
__device__ __forceinline__ void store_split(unsigned short* __restrict__ ph,
                                            unsigned short* __restrict__ pl,
                                            size_t idx, float v) {
  unsigned short h = f2bf(v);
  ph[idx] = h;
  pl[idx] = f2bf(v - bf2f(h));
}

// ============================ CSR construction =============================
__global__ __launch_bounds__(256) void hist_k(const int* __restrict__ ei,
                                              int* __restrict__ deg) {
  int e = blockIdx.x * 256 + threadIdx.x;
  if (e < N_EDGES) atomicAdd(&deg[ei[N_EDGES + e]], 1);
}

__global__ __launch_bounds__(256) void scan_blk(const int* __restrict__ deg,
                                                int* __restrict__ roff,
                                                int* __restrict__ bsum) {
  __shared__ int s[256];
  int i = blockIdx.x * 256 + threadIdx.x;
  int v = (i < N_NODES) ? deg[i] : 0;
  s[threadIdx.x] = v;
  __syncthreads();
  #pragma unroll
  for (int o = 1; o < 256; o <<= 1) {
    int t = (threadIdx.x >= o) ? s[threadIdx.x - o] : 0;
    __syncthreads();
    s[threadIdx.x] += t;
    __syncthreads();
  }
  if (i < N_NODES) roff[i] = s[threadIdx.x] - v;   // exclusive
  if (threadIdx.x == 255) bsum[blockIdx.x] = s[255];
}

__global__ __launch_bounds__(256) void scan_top(int* __restrict__ bsum) {
  __shared__ int s[256];
  int i = threadIdx.x;
  int v = (i < NBLK_SCAN) ? bsum[i] : 0;
  s[i] = v;
  __syncthreads();
  #pragma unroll
  for (int o = 1; o < 256; o <<= 1) {
    int t = (i >= o) ? s[i - o] : 0;
    __syncthreads();
    s[i] += t;
    __syncthreads();
  }
  if (i < NBLK_SCAN) bsum[i] = s[i] - v;           // exclusive
}

__global__ __launch_bounds__(256) void scan_add(int* __restrict__ roff,
                                                const int* __restrict__ bsum) {
  int i = blockIdx.x * 256 + threadIdx.x;
  if (i < N_NODES) roff[i] += bsum[blockIdx.x];
  if (i == 0) roff[N_NODES] = N_EDGES;
}

__global__ __launch_bounds__(256) void scatter_k(const int* __restrict__ ei,
                                                 const int* __restrict__ roff,
                                                 int* __restrict__ cursor,
                                                 int* __restrict__ ssrc) {
  int e = blockIdx.x * 256 + threadIdx.x;
  if (e >= N_EDGES) return;
  int dst = ei[N_EDGES + e];
  int pos = roff[dst] + atomicAdd(&cursor[dst], 1);
  ssrc[pos] = ei[e];
}

// =================== bf16 hi/lo conversions for MFMA GEMMs =================
__global__ __launch_bounds__(256) void conv_x(const float* __restrict__ X,
                                              unsigned short* __restrict__ Xh,
                                              unsigned short* __restrict__ Xl) {
  int i = blockIdx.x * 256 + threadIdx.x;          // float4 index
  if (i >= N_NODES * IN_CH / 4) return;
  float4 v = reinterpret_cast<const float4*>(X)[i];
  ushort4 h, l;
  h.x = f2bf(v.x); l.x = f2bf(v.x - bf2f(h.x));
  h.y = f2bf(v.y); l.y = f2bf(v.y - bf2f(h.y));
  h.z = f2bf(v.z); l.z = f2bf(v.z - bf2f(h.z));
  h.w = f2bf(v.w); l.w = f2bf(v.w - bf2f(h.w));
  reinterpret_cast<ushort4*>(Xh)[i] = h;
  reinterpret_cast<ushort4*>(Xl)[i] = l;
}

// W1[128][320] -> W1T[320][128] hi/lo ; W2[320][32] -> W2T[32][320] hi/lo
__global__ __launch_bounds__(256) void conv_w(const float* __restrict__ W1,
                                              const float* __restrict__ W2,
                                              unsigned short* __restrict__ W1hT,
                                              unsigned short* __restrict__ W1lT,
                                              unsigned short* __restrict__ W2hT,
                                              unsigned short* __restrict__ W2lT) {
  int i = blockIdx.x * 256 + threadIdx.x;
  if (i < IN_CH * HC) {                 // i = n*128 + k
    int n = i >> 7, k = i & 127;
    float v = W1[(size_t)k * HC + n];
    unsigned short h = f2bf(v);
    W1hT[i] = h; W1lT[i] = f2bf(v - bf2f(h));
  } else {
    int j = i - IN_CH * HC;
    if (j < OUT_CH * HC) {              // j = c*320 + k
      int c = j / HC, k = j - c * HC;
      float v = W2[(size_t)k * OUT_CH + c];
      unsigned short h = f2bf(v);
      W2hT[j] = h; W2lT[j] = f2bf(v - bf2f(h));
    }
  }
}

// ======== GEMM1 via MFMA split-bf16: h1b[N,320](bf16) = X @ W1 =============
// wave -> one 16x16 C tile; frags direct from global.
// C/D: col=lane&15, row=(lane>>4)*4+reg  [verified m89]
__global__ __launch_bounds__(256) void gemm1_mfma(const unsigned short* __restrict__ Xh,
                                                  const unsigned short* __restrict__ Xl,
                                                  const unsigned short* __restrict__ WhT,
                                                  const unsigned short* __restrict__ WlT,
                                                  unsigned short* __restrict__ Hb) {
  const int wave = threadIdx.x >> 6;
  const int lane = threadIdx.x & 63;
  const int col0 = blockIdx.x * 16;                  // 20 col tiles
  const int row0 = blockIdx.y * 64 + wave * 16;
  const int r = lane & 15;
  const int kg = lane >> 4;                          // 0..3
  int arow = row0 + r; if (arow >= N_NODES) arow = N_NODES - 1;
  const unsigned short* xh = Xh + (size_t)arow * IN_CH + kg * 8;
  const unsigned short* xl = Xl + (size_t)arow * IN_CH + kg * 8;
  const unsigned short* wh = WhT + (size_t)(col0 + r) * IN_CH + kg * 8;
  const unsigned short* wl = WlT + (size_t)(col0 + r) * IN_CH + kg * 8;
  f32x4 acc = {0.f, 0.f, 0.f, 0.f};
  #pragma unroll
  for (int k0 = 0; k0 < IN_CH; k0 += 32) {
    bf16x8 ah = *reinterpret_cast<const bf16x8*>(xh + k0);
    bf16x8 al = *reinterpret_cast<const bf16x8*>(xl + k0);
    bf16x8 bh = *reinterpret_cast<const bf16x8*>(wh + k0);
    bf16x8 bl = *reinterpret_cast<const bf16x8*>(wl + k0);
    acc = __builtin_amdgcn_mfma_f32_16x16x32_bf16(ah, bh, acc, 0, 0, 0);
    acc = __builtin_amdgcn_mfma_f32_16x16x32_bf16(ah, bl, acc, 0, 0, 0);
    acc = __builtin_amdgcn_mfma_f32_16x16x32_bf16(al, bh, acc, 0, 0, 0);
  }
  const int crow0 = row0 + kg * 4;
  const int ccol = col0 + r;
  #pragma unroll
  for (int t = 0; t < 4; t++) {
    int rr = crow0 + t;
    if (rr < N_NODES) Hb[(size_t)rr * HC + ccol] = f2bf(acc[t]);
  }
}

// ======== GEMM2 via MFMA split-bf16: h2[N,32](f32) = act @ W2 ==============
__global__ __launch_bounds__(256) void gemm2_mfma(const unsigned short* __restrict__ Ah,
                                                  const unsigned short* __restrict__ Al,
                                                  const unsigned short* __restrict__ WhT,
                                                  const unsigned short* __restrict__ WlT,
                                                  float* __restrict__ H) {
  const int wave = threadIdx.x >> 6;
  const int lane = threadIdx.x & 63;
  const int col0 = blockIdx.x * 16;                  // 2 col tiles
  const int row0 = blockIdx.y * 64 + wave * 16;
  const int r = lane & 15;
  const int kg = lane >> 4;
  int arow = row0 + r; if (arow >= N_NODES) arow = N_NODES - 1;
  const unsigned short* ah_p = Ah + (size_t)arow * HC + kg * 8;
  const unsigned short* al_p = Al + (size_t)arow * HC + kg * 8;
  const unsigned short* wh = WhT + (size_t)(col0 + r) * HC + kg * 8;
  const unsigned short* wl = WlT + (size_t)(col0 + r) * HC + kg * 8;
  f32x4 acc = {0.f, 0.f, 0.f, 0.f};
  #pragma unroll
  for (int k0 = 0; k0 < HC; k0 += 32) {
    bf16x8 ah = *reinterpret_cast<const bf16x8*>(ah_p + k0);
    bf16x8 al = *reinterpret_cast<const bf16x8*>(al_p + k0);
    bf16x8 bh = *reinterpret_cast<const bf16x8*>(wh + k0);
    bf16x8 bl = *reinterpret_cast<const bf16x8*>(wl + k0);
    acc = __builtin_amdgcn_mfma_f32_16x16x32_bf16(ah, bh, acc, 0, 0, 0);
    acc = __builtin_amdgcn_mfma_f32_16x16x32_bf16(ah, bl, acc, 0, 0, 0);
    acc = __builtin_amdgcn_mfma_f32_16x16x32_bf16(al, bh, acc, 0, 0, 0);
  }
  const int crow0 = row0 + kg * 4;
  const int ccol = col0 + r;
  #pragma unroll
  for (int t = 0; t < 4; t++) {
    int rr = crow0 + t;
    if (rr < N_NODES) H[(size_t)rr * OUT_CH + ccol] = acc[t];
  }
}

// --- e_src/e_dst per (node, head): dot(h1b[n,h,:], a_src[h,:]) (bf16 h1) ---
__global__ __launch_bounds__(256) void edot1(const unsigned short* __restrict__ h1b,
                                             const float* __restrict__ a_src,
                                             const float* __restrict__ a_dst,
                                             float* __restrict__ es,
                                             float* __restrict__ ed) {
  int idx = blockIdx.x * 256 + threadIdx.x;
  if (idx >= N_NODES * HEADS) return;
  int n = idx / HEADS, h = idx - n * HEADS;
  const uint4* hp = reinterpret_cast<const uint4*>(h1b + (size_t)n * HC + h * OUT_CH);
  const float2* ap = reinterpret_cast<const float2*>(a_src + h * OUT_CH);
  const float2* bp = reinterpret_cast<const float2*>(a_dst + h * OUT_CH);
  float s = 0.f, d = 0.f;
  #pragma unroll
  for (int q = 0; q < 4; q++) {                      // 8 bf16 per uint4
    uint4 u = hp[q];
    unsigned w[4] = {u.x, u.y, u.z, u.w};
    #pragma unroll
    for (int k = 0; k < 4; k++) {
      float lo = bflo(w[k]), hi = bfhi(w[k]);
      float2 av = ap[q * 4 + k], bv = bp[q * 4 + k];
      s += lo * av.x + hi * av.y;
      d += lo * bv.x + hi * bv.y;
    }
  }
  es[idx] = s; ed[idx] = d;
}

// ------ layer-1 aggregation: one wave per dst node, wave-coop softmax ------
// lane covers cols t = lane + 64q (q=0..4); head of (lane,q) = 2q + (lane>>5)
// h1 gathered as bf16 (half traffic); epilogue writes act hi/lo splits.
__global__ __launch_bounds__(256) void agg1(const int* __restrict__ roff,
                                            const int* __restrict__ ssrc,
                                            const float* __restrict__ es,
                                            const float* __restrict__ ed,
                                            const unsigned short* __restrict__ h1b,
                                            const float* __restrict__ b1,
                                            unsigned short* __restrict__ acth,
                                            unsigned short* __restrict__ actl) {
  __shared__ float lds[4][64][11];   // [wave][edge][0..9]=ex, [10]=src bits
  const int n = (blockIdx.x * 256 + threadIdx.x) >> 6;
  if (n >= N_NODES) return;
  const int wslot = threadIdx.x >> 6;
  const int lane = threadIdx.x & 63;
  const int hb = lane >> 5;                 // 0 or 1
  const int beg = roff[n];
  const int deg = roff[n + 1] - beg;

  if (deg == 0) {
    #pragma unroll
    for (int q = 0; q < 5; q++) {
      float v = b1[lane + 64 * q];
      v = v > 0.f ? v : expm1f(v);
      store_split(acth, actl, (size_t)n * HC + lane + 64 * q, v);
    }
    return;
  }

  float acc[5] = {};

  if (deg <= 64) {
    // ---- phase 1: lane e owns edge e; compute 10 alphas in registers ----
    const int active = (lane < deg);
    const int src = ssrc[beg + (active ? lane : 0)];
    float a[10];
    #pragma unroll
    for (int p = 0; p < 5; p++) {
      float2 edp = *reinterpret_cast<const float2*>(ed + n * 10 + 2 * p);
      float2 esp = *reinterpret_cast<const float2*>(es + src * 10 + 2 * p);
      a[2 * p]     = active ? leaky(esp.x + edp.x) : -1e30f;
      a[2 * p + 1] = active ? leaky(esp.y + edp.y) : -1e30f;
    }
    // per-head wave max
    float m[10];
    #pragma unroll
    for (int h = 0; h < 10; h++) m[h] = a[h];
    #pragma unroll
    for (int o = 1; o < 64; o <<= 1)
      #pragma unroll
      for (int h = 0; h < 10; h++) m[h] = fmaxf(m[h], __shfl_xor(m[h], o));
    // exp, park in LDS; per-head wave denom
    float d[10];
    #pragma unroll
    for (int h = 0; h < 10; h++) {
      float ex = expf(a[h] - m[h]);        // 0 for inactive lanes
      lds[wslot][lane][h] = ex;
      d[h] = ex;
    }
    lds[wslot][lane][10] = __int_as_float(src);
    #pragma unroll
    for (int o = 1; o < 64; o <<= 1)
      #pragma unroll
      for (int h = 0; h < 10; h++) d[h] += __shfl_xor(d[h], o);

    // ---- phase 2: gather bf16 h1 rows weighted by LDS-broadcast coefs ----
    int j = 0;
    for (; j + 4 <= deg; j += 4) {
      int s0 = __float_as_int(lds[wslot][j + 0][10]);
      int s1 = __float_as_int(lds[wslot][j + 1][10]);
      int s2 = __float_as_int(lds[wslot][j + 2][10]);
      int s3 = __float_as_int(lds[wslot][j + 3][10]);
      const unsigned short* __restrict__ r0 = h1b + (size_t)s0 * HC + lane;
      const unsigned short* __restrict__ r1 = h1b + (size_t)s1 * HC + lane;
      const unsigned short* __restrict__ r2 = h1b + (size_t)s2 * HC + lane;
      const unsigned short* __restrict__ r3 = h1b + (size_t)s3 * HC + lane;
      float v0[5], v1[5], v2[5], v3[5];
      #pragma unroll
      for (int q = 0; q < 5; q++) v0[q] = bf2f(r0[64 * q]);
      #pragma unroll
      for (int q = 0; q < 5; q++) v1[q] = bf2f(r1[64 * q]);
      #pragma unroll
      for (int q = 0; q < 5; q++) v2[q] = bf2f(r2[64 * q]);
      #pragma unroll
      for (int q = 0; q < 5; q++) v3[q] = bf2f(r3[64 * q]);
      #pragma unroll
      for (int q = 0; q < 5; q++) {
        acc[q] = fmaf(v0[q], lds[wslot][j + 0][2 * q + hb], acc[q]);
        acc[q] = fmaf(v1[q], lds[wslot][j + 1][2 * q + hb], acc[q]);
        acc[q] = fmaf(v2[q], lds[wslot][j + 2][2 * q + hb], acc[q]);
        acc[q] = fmaf(v3[q], lds[wslot][j + 3][2 * q + hb], acc[q]);
      }
    }
    for (; j < deg; j++) {
      int sj = __float_as_int(lds[wslot][j][10]);
      const unsigned short* __restrict__ hrow = h1b + (size_t)sj * HC + lane;
      #pragma unroll
      for (int q = 0; q < 5; q++)
        acc[q] = fmaf(bf2f(hrow[64 * q]), lds[wslot][j][2 * q + hb], acc[q]);
    }
    #pragma unroll
    for (int q = 0; q < 5; q++) {
      float v = acc[q] / (d[2 * q + hb] + 1e-16f) + b1[lane + 64 * q];
      v = v > 0.f ? v : expm1f(v);
      store_split(acth, actl, (size_t)n * HC + lane + 64 * q, v);
    }
  } else {
    // ---- slow fallback (deg > 64): per-lane redundant 2-pass ----
    float edv[5], m2[5];
    #pragma unroll
    for (int q = 0; q < 5; q++) { edv[q] = ed[n * 10 + 2 * q + hb]; m2[q] = -1e30f; }
    for (int j = beg; j < beg + deg; j++) {
      int src = ssrc[j];
      #pragma unroll
      for (int q = 0; q < 5; q++)
        m2[q] = fmaxf(m2[q], leaky(es[src * 10 + 2 * q + hb] + edv[q]));
    }
    float d2[5] = {};
    for (int j = beg; j < beg + deg; j++) {
      int src = ssrc[j];
      const unsigned short* hrow = h1b + (size_t)src * HC + lane;
      #pragma unroll
      for (int q = 0; q < 5; q++) {
        float ex = expf(leaky(es[src * 10 + 2 * q + hb] + edv[q]) - m2[q]);
        acc[q] = fmaf(bf2f(hrow[64 * q]), ex, acc[q]);
        d2[q] += ex;
      }
    }
    #pragma unroll
    for (int q = 0; q < 5; q++) {
      float v = acc[q] / (d2[q] + 1e-16f) + b1[lane + 64 * q];
      v = v > 0.f ? v : expm1f(v);
      store_split(acth, actl, (size_t)n * HC + lane + 64 * q, v);
    }
  }
}

// ---------------- e_src2/e_dst2 per node (H=1) -----------------------------
__global__ __launch_bounds__(256) void edot2(const float* __restrict__ h2,
                                             const float* __restrict__ a_src,
                                             const float* __restrict__ a_dst,
                                             float* __restrict__ es,
                                             float* __restrict__ ed) {
  int n = blockIdx.x * 256 + threadIdx.x;
  if (n >= N_NODES) return;
  const float4* hp = reinterpret_cast<const float4*>(h2 + (size_t)n * OUT_CH);
  const float4* ap = reinterpret_cast<const float4*>(a_src);
  const float4* bp = reinterpret_cast<const float4*>(a_dst);
  float s = 0.f, d = 0.f;
  #pragma unroll
  for (int q = 0; q < 8; q++) {
    float4 hv = hp[q], av = ap[q], dv = bp[q];
    s += hv.x * av.x + hv.y * av.y + hv.z * av.z + hv.w * av.w;
    d += hv.x * dv.x + hv.y * dv.y + hv.z * dv.z + hv.w * dv.w;
  }
  es[n] = s; ed[n] = d;
}

// ------ layer-2 aggregation: one wave per node, unrolled, fused pool -------
__global__ __launch_bounds__(256) void agg2(const int* __restrict__ roff,
                                            const int* __restrict__ ssrc,
                                            const float* __restrict__ es,
                                            const float* __restrict__ ed,
                                            const float* __restrict__ h2,
                                            const float* __restrict__ b2,
                                            const int* __restrict__ batch,
                                            unsigned* __restrict__ pooled) {
  __shared__ float lds[4][64][2];    // [wave][edge][0]=ex, [1]=src bits
  const int n = (blockIdx.x * 256 + threadIdx.x) >> 6;
  if (n >= N_NODES) return;
  const int wslot = threadIdx.x >> 6;
  const int lane = threadIdx.x & 63;
  const int c = lane & 31;
  const int hb = lane >> 5;
  const int beg = roff[n];
  const int deg = roff[n + 1] - beg;
  const int g = batch[n];

  if (deg == 0) {
    if (lane < 32) {
      float v = b2[c];
      v = v > 0.f ? v : expm1f(v);
      atomicMax(&pooled[g * OUT_CH + c], fmap(v));
    }
    return;
  }

  float acc = 0.f, dtot;

  if (deg <= 64) {
    const int active = (lane < deg);
    const int src = ssrc[beg + (active ? lane : 0)];
    const float edv = ed[n];
    float a = active ? leaky(es[src] + edv) : -1e30f;
    float m = a;
    #pragma unroll
    for (int o = 1; o < 64; o <<= 1) m = fmaxf(m, __shfl_xor(m, o));
    float ex = expf(a - m);
    float d = ex;
    #pragma unroll
    for (int o = 1; o < 64; o <<= 1) d += __shfl_xor(d, o);
    dtot = d;
    lds[wslot][lane][0] = ex;
    lds[wslot][lane][1] = __int_as_float(src);
    int j = hb;
    for (; j + 6 < deg; j += 8) {
      int s0 = __float_as_int(lds[wslot][j + 0][1]);
      int s1 = __float_as_int(lds[wslot][j + 2][1]);
      int s2 = __float_as_int(lds[wslot][j + 4][1]);
      int s3 = __float_as_int(lds[wslot][j + 6][1]);
      float c0 = lds[wslot][j + 0][0];
      float c1 = lds[wslot][j + 2][0];
      float c2 = lds[wslot][j + 4][0];
      float c3 = lds[wslot][j + 6][0];
      float v0 = h2[(size_t)s0 * OUT_CH + c];
      float v1 = h2[(size_t)s1 * OUT_CH + c];
      float v2 = h2[(size_t)s2 * OUT_CH + c];
      float v3 = h2[(size_t)s3 * OUT_CH + c];
      acc = fmaf(v0, c0, acc);
      acc = fmaf(v1, c1, acc);
      acc = fmaf(v2, c2, acc);
      acc = fmaf(v3, c3, acc);
    }
    for (; j < deg; j += 2) {
      int sj = __float_as_int(lds[wslot][j][1]);
      acc = fmaf(h2[(size_t)sj * OUT_CH + c], lds[wslot][j][0], acc);
    }
  } else {
    const float edv = ed[n];
    float m = -1e30f;
    for (int j = beg; j < beg + deg; j++)
      m = fmaxf(m, leaky(es[ssrc[j]] + edv));
    float d = 0.f;
    for (int j = beg + hb; j < beg + deg; j += 2) {
      int src = ssrc[j];
      float ex = expf(leaky(es[src] + edv) - m);
      acc = fmaf(h2[(size_t)src * OUT_CH + c], ex, acc);
      d += ex;
    }
    d += __shfl_xor(d, 32);
    dtot = d;
  }

  acc += __shfl_xor(acc, 32);
  if (lane < 32) {
    float v = acc / (dtot + 1e-16f) + b2[c];
    v = v > 0.f ? v : expm1f(v);
    atomicMax(&pooled[g * OUT_CH + c], fmap(v));
  }
}

// -------- final: out[g,c] = relu(pooled[g,:] @ fc_w[:,c] + fc_b[c]) --------
__global__ __launch_bounds__(256) void final_k(const unsigned* __restrict__ pooled,
                                               const float* __restrict__ fc_w,
                                               const float* __restrict__ fc_b,
                                               float* __restrict__ out) {
  int idx = blockIdx.x * 256 + threadIdx.x;
  if (idx >= N_GRAPHS * OUT_CH) return;
  int g = idx >> 5, c = idx & 31;
  float s = fc_b[c];
  #pragma unroll
  for (int k = 0; k < OUT_CH; k++) {
    unsigned u = pooled[g * OUT_CH + k];
    float p = (u == 0u) ? 0.f : funmap(u);
    s += p * fc_w[k * OUT_CH + c];
  }
  out[idx] = s > 0.f ? s : 0.f;
}

extern "C" void kernel_launch(void* const* d_in, const int* in_sizes, int n_in,
                              void* d_out, int out_size, void* d_ws, size_t ws_size,
                              hipStream_t stream) {
  const float* x      = (const float*)d_in[0];
  const int*   ei     = (const int*)d_in[1];
  const int*   batch  = (const int*)d_in[2];
  const float* W1     = (const float*)d_in[4];
  const float* a_src1 = (const float*)d_in[5];
  const float* a_dst1 = (const float*)d_in[6];
  const float* b1     = (const float*)d_in[7];
  const float* W2     = (const float*)d_in[8];
  const float* a_src2 = (const float*)d_in[9];
  const float* a_dst2 = (const float*)d_in[10];
  const float* b2     = (const float*)d_in[11];
  const float* fc_w   = (const float*)d_in[12];
  const float* fc_b   = (const float*)d_in[13];
  float* out = (float*)d_out;

  // ---- workspace layout (<= 136 MB, phase-aliased) ----
  // A [0,64M):   h1b bf16 32MB (gemm1->edot1->agg1); h2 f32 reuses after agg1
  // B [64M,128M): phase1 Xh|Xl (25.6M); phase2 act_h|act_l (64M)
  // S [128M,136M): CSR + es/ed + pooled; W-splits alias dead deg/cursor
  char* ws = (char*)d_ws;
  unsigned short* h1b = (unsigned short*)(ws);              // 32 MB
  float* h2   = (float*)(ws);                               // after agg1
  unsigned short* Xh   = (unsigned short*)(ws + 64000000);  // 12.8 MB
  unsigned short* Xl   = (unsigned short*)(ws + 76800000);  // 12.8 MB
  unsigned short* acth = (unsigned short*)(ws + 64000000);  // 32 MB (after gemm1)
  unsigned short* actl = (unsigned short*)(ws + 96000000);  // 32 MB
  char*  S    = ws + 128000000;
  int*   ssrc   = (int*)(S);                  // 3.2 MB
  int*   roff   = (int*)(S + 3200000);        // 200,004 B
  int*   deg    = (int*)(S + 3400064);        // 200,000 B (dead after scan)
  int*   cursor = (int*)(S + 3600064);        // 200,000 B (dead after scatter)
  unsigned short* W1hT = (unsigned short*)(S + 3400064);            // 81,920 B
  unsigned short* W1lT = (unsigned short*)(S + 3400064 + 81920);    // 81,920 B
  unsigned short* W2hT = (unsigned short*)(S + 3400064 + 163840);   // 20,480 B
  unsigned short* W2lT = (unsigned short*)(S + 3400064 + 184320);   // 20,480 B
  float* es1    = (float*)(S + 3800064);      // 2 MB
  float* ed1    = (float*)(S + 5800064);      // 2 MB
  int*   bsum   = (int*)(S + 7800064);        // 784 B
  unsigned* pooled = (unsigned*)(S + 7801600);// 64 KB
  float* es2 = es1; float* ed2 = ed1;         // dead after agg1

  // ---- CSR build ----
  hipMemsetAsync(deg, 0, (size_t)N_NODES * 4, stream);
  hipMemsetAsync(cursor, 0, (size_t)N_NODES * 4, stream);
  hist_k   <<<(N_EDGES + 255) / 256, 256, 0, stream>>>(ei, deg);
  scan_blk <<<NBLK_SCAN, 256, 0, stream>>>(deg, roff, bsum);
  scan_top <<<1, 256, 0, stream>>>(bsum);
  scan_add <<<NBLK_SCAN, 256, 0, stream>>>(roff, bsum);
  scatter_k<<<(N_EDGES + 255) / 256, 256, 0, stream>>>(ei, roff, cursor, ssrc);

  // ---- bf16 splits (conv_w AFTER scatter: aliases deg/cursor) ----
  conv_x<<<(N_NODES * IN_CH / 4 + 255) / 256, 256, 0, stream>>>(x, Xh, Xl);
  conv_w<<<(IN_CH * HC + OUT_CH * HC + 255) / 256, 256, 0, stream>>>(
      W1, W2, W1hT, W1lT, W2hT, W2lT);

  // ---- layer 1 ----
  gemm1_mfma<<<dim3(HC / 16, (N_NODES + 63) / 64), 256, 0, stream>>>(
      Xh, Xl, W1hT, W1lT, h1b);
  edot1<<<(N_NODES * HEADS + 255) / 256, 256, 0, stream>>>(h1b, a_src1, a_dst1, es1, ed1);
  agg1 <<<(N_NODES * 64 + 255) / 256, 256, 0, stream>>>(roff, ssrc, es1, ed1, h1b, b1,
                                                        acth, actl);

  // ---- layer 2 ----
  hipMemsetAsync(pooled, 0, (size_t)N_GRAPHS * OUT_CH * 4, stream);
  gemm2_mfma<<<dim3(OUT_CH / 16, (N_NODES + 63) / 64), 256, 0, stream>>>(
      acth, actl, W2hT, W2lT, h2);
  edot2<<<(N_NODES + 255) / 256, 256, 0, stream>>>(h2, a_src2, a_dst2, es2, ed2);
  agg2 <<<(N_NODES * 64 + 255) / 256, 256, 0, stream>>>(roff, ssrc, es2, ed2, h2, b2,
                                                        batch, pooled);
  final_k<<<(N_GRAPHS * OUT_CH + 255) / 256, 256, 0, stream>>>(pooled, fc_w, fc_b, out);
}

// Round 13
// 377.065 us; speedup vs baseline: 1.2563x; 1.0898x over previous
//
#include <hip/hip_runtime.h>

#define N_NODES 50000
#define N_EDGES 800000
#define IN_CH   128
#define OUT_CH  32
#define HEADS   10
#define HC      320           // HEADS*OUT_CH
#define N_GRAPHS 512
#define NEG_SLOPE 0.2f
#define NBLK_SCAN 196         // ceil(50000/256)

typedef __attribute__((ext_vector_type(8))) short bf16x8;   // 8 bf16 in 4 VGPRs
typedef __attribute__((ext_vector_type(4))) float f32x4;

// ---- order-preserving float<->uint map for atomicMax-based segment_max ----
__device__ __forceinline__ unsigned fmap(float f) {
  unsigned u = __float_as_uint(f);
  return (u & 0x80000000u) ? ~u : (u | 0x80000000u);
}
__device__ __forceinline__ float funmap(unsigned u) {
  u = (u & 0x80000000u) ? (u ^ 0x80000000u) : ~u;
  return __uint_as_float(u);
}
__device__ __forceinline__ float leaky(float a) {
  return a > 0.f ? a : NEG_SLOPE * a;
}
// ---- bf16 helpers (RNE) + hi/lo split store ----
__device__ __forceinline__ unsigned short f2bf(float f) {
  unsigned u = __float_as_uint(f);
  return (unsigned short)((u + 0x7FFFu + ((u >> 16) & 1u)) >> 16);
}
__device__ __forceinline__ float bf2f(unsigned short b) {
  return __uint_as_float(((unsigned)b) << 16);
}
// packed-pair unpack: uint holds bf16 c=2i (low16) and c=2i+1 (high16)
__device__ __forceinline__ float bflo(unsigned u) { return __uint_as_float(u << 16); }
__device__ __forceinline__ float bfhi(unsigned u) { return __uint_as_float(u & 0xFFFF0000u); }
__device__ __forceinline__ void store_split(unsigned short* __restrict__ ph,
                                            unsigned short* __restrict__ pl,
                                            size_t idx, float v) {
  unsigned short h = f2bf(v);
  ph[idx] = h;
  pl[idx] = f2bf(v - bf2f(h));
}

// ============================ CSR construction =============================
__global__ __launch_bounds__(256) void hist_k(const int* __restrict__ ei,
                                              int* __restrict__ deg) {
  int e = blockIdx.x * 256 + threadIdx.x;
  if (e < N_EDGES) atomicAdd(&deg[ei[N_EDGES + e]], 1);
}

__global__ __launch_bounds__(256) void scan_blk(const int* __restrict__ deg,
                                                int* __restrict__ roff,
                                                int* __restrict__ bsum) {
  __shared__ int s[256];
  int i = blockIdx.x * 256 + threadIdx.x;
  int v = (i < N_NODES) ? deg[i] : 0;
  s[threadIdx.x] = v;
  __syncthreads();
  #pragma unroll
  for (int o = 1; o < 256; o <<= 1) {
    int t = (threadIdx.x >= o) ? s[threadIdx.x - o] : 0;
    __syncthreads();
    s[threadIdx.x] += t;
    __syncthreads();
  }
  if (i < N_NODES) roff[i] = s[threadIdx.x] - v;   // exclusive
  if (threadIdx.x == 255) bsum[blockIdx.x] = s[255];
}

__global__ __launch_bounds__(256) void scan_top(int* __restrict__ bsum) {
  __shared__ int s[256];
  int i = threadIdx.x;
  int v = (i < NBLK_SCAN) ? bsum[i] : 0;
  s[i] = v;
  __syncthreads();
  #pragma unroll
  for (int o = 1; o < 256; o <<= 1) {
    int t = (i >= o) ? s[i - o] : 0;
    __syncthreads();
    s[i] += t;
    __syncthreads();
  }
  if (i < NBLK_SCAN) bsum[i] = s[i] - v;           // exclusive
}

__global__ __launch_bounds__(256) void scan_add(int* __restrict__ roff,
                                                const int* __restrict__ bsum) {
  int i = blockIdx.x * 256 + threadIdx.x;
  if (i < N_NODES) roff[i] += bsum[blockIdx.x];
  if (i == 0) roff[N_NODES] = N_EDGES;
}

__global__ __launch_bounds__(256) void scatter_k(const int* __restrict__ ei,
                                                 const int* __restrict__ roff,
                                                 int* __restrict__ cursor,
                                                 int* __restrict__ ssrc) {
  int e = blockIdx.x * 256 + threadIdx.x;
  if (e >= N_EDGES) return;
  int dst = ei[N_EDGES + e];
  int pos = roff[dst] + atomicAdd(&cursor[dst], 1);
  ssrc[pos] = ei[e];
}

// =================== bf16 hi/lo conversions for MFMA GEMMs =================
__global__ __launch_bounds__(256) void conv_x(const float* __restrict__ X,
                                              unsigned short* __restrict__ Xh,
                                              unsigned short* __restrict__ Xl) {
  int i = blockIdx.x * 256 + threadIdx.x;          // float4 index
  if (i >= N_NODES * IN_CH / 4) return;
  float4 v = reinterpret_cast<const float4*>(X)[i];
  ushort4 h, l;
  h.x = f2bf(v.x); l.x = f2bf(v.x - bf2f(h.x));
  h.y = f2bf(v.y); l.y = f2bf(v.y - bf2f(h.y));
  h.z = f2bf(v.z); l.z = f2bf(v.z - bf2f(h.z));
  h.w = f2bf(v.w); l.w = f2bf(v.w - bf2f(h.w));
  reinterpret_cast<ushort4*>(Xh)[i] = h;
  reinterpret_cast<ushort4*>(Xl)[i] = l;
}

// W1[128][320] -> W1T[320][128] hi/lo ; W2[320][32] -> W2T[32][320] hi/lo
__global__ __launch_bounds__(256) void conv_w(const float* __restrict__ W1,
                                              const float* __restrict__ W2,
                                              unsigned short* __restrict__ W1hT,
                                              unsigned short* __restrict__ W1lT,
                                              unsigned short* __restrict__ W2hT,
                                              unsigned short* __restrict__ W2lT) {
  int i = blockIdx.x * 256 + threadIdx.x;
  if (i < IN_CH * HC) {                 // i = n*128 + k
    int n = i >> 7, k = i & 127;
    float v = W1[(size_t)k * HC + n];
    unsigned short h = f2bf(v);
    W1hT[i] = h; W1lT[i] = f2bf(v - bf2f(h));
  } else {
    int j = i - IN_CH * HC;
    if (j < OUT_CH * HC) {              // j = c*320 + k
      int c = j / HC, k = j - c * HC;
      float v = W2[(size_t)k * OUT_CH + c];
      unsigned short h = f2bf(v);
      W2hT[j] = h; W2lT[j] = f2bf(v - bf2f(h));
    }
  }
}

// ======== GEMM1 via MFMA split-bf16: h1b[N,320](bf16) = X @ W1 =============
// block = 64-row x 320-col strip; wave = 16 rows x 20 col-tiles.
// A frags loaded ONCE per k-step, reused across all 20 col-tiles (20x less
// A traffic than tile-per-wave). B (160KB) is L2-resident.
// C/D: col=lane&15, row=(lane>>4)*4+reg  [verified m89]
__global__ __launch_bounds__(256) void gemm1_mfma(const unsigned short* __restrict__ Xh,
                                                  const unsigned short* __restrict__ Xl,
                                                  const unsigned short* __restrict__ WhT,
                                                  const unsigned short* __restrict__ WlT,
                                                  unsigned short* __restrict__ Hb) {
  const int wave = threadIdx.x >> 6;
  const int lane = threadIdx.x & 63;
  const int row0 = blockIdx.x * 64 + wave * 16;
  const int r = lane & 15;
  const int kg = lane >> 4;                          // 0..3
  int arow = row0 + r; if (arow >= N_NODES) arow = N_NODES - 1;
  const unsigned short* xh = Xh + (size_t)arow * IN_CH + kg * 8;
  const unsigned short* xl = Xl + (size_t)arow * IN_CH + kg * 8;
  const unsigned short* wb = WhT + (size_t)r * IN_CH + kg * 8;   // col-tile 0
  const unsigned short* lb = WlT + (size_t)r * IN_CH + kg * 8;
  f32x4 acc[20];
  #pragma unroll
  for (int c = 0; c < 20; c++) acc[c] = f32x4{0.f, 0.f, 0.f, 0.f};
  #pragma unroll
  for (int k0 = 0; k0 < IN_CH; k0 += 32) {
    bf16x8 ah = *reinterpret_cast<const bf16x8*>(xh + k0);
    bf16x8 al = *reinterpret_cast<const bf16x8*>(xl + k0);
    #pragma unroll
    for (int c = 0; c < 20; c++) {
      bf16x8 bh = *reinterpret_cast<const bf16x8*>(wb + (size_t)c * 16 * IN_CH + k0);
      bf16x8 bl = *reinterpret_cast<const bf16x8*>(lb + (size_t)c * 16 * IN_CH + k0);
      acc[c] = __builtin_amdgcn_mfma_f32_16x16x32_bf16(ah, bh, acc[c], 0, 0, 0);
      acc[c] = __builtin_amdgcn_mfma_f32_16x16x32_bf16(ah, bl, acc[c], 0, 0, 0);
      acc[c] = __builtin_amdgcn_mfma_f32_16x16x32_bf16(al, bh, acc[c], 0, 0, 0);
    }
  }
  const int crow0 = row0 + kg * 4;
  #pragma unroll
  for (int c = 0; c < 20; c++) {
    const int ccol = c * 16 + r;
    #pragma unroll
    for (int t = 0; t < 4; t++) {
      int rr = crow0 + t;
      if (rr < N_NODES) Hb[(size_t)rr * HC + ccol] = f2bf(acc[c][t]);
    }
  }
}

// ======== GEMM2 via MFMA split-bf16: h2[N,32](f32) = act @ W2 ==============
// block = 64-row x 32-col strip; wave = 16 rows x 2 col-tiles (A read once).
__global__ __launch_bounds__(256) void gemm2_mfma(const unsigned short* __restrict__ Ah,
                                                  const unsigned short* __restrict__ Al,
                                                  const unsigned short* __restrict__ WhT,
                                                  const unsigned short* __restrict__ WlT,
                                                  float* __restrict__ H) {
  const int wave = threadIdx.x >> 6;
  const int lane = threadIdx.x & 63;
  const int row0 = blockIdx.x * 64 + wave * 16;
  const int r = lane & 15;
  const int kg = lane >> 4;
  int arow = row0 + r; if (arow >= N_NODES) arow = N_NODES - 1;
  const unsigned short* ah_p = Ah + (size_t)arow * HC + kg * 8;
  const unsigned short* al_p = Al + (size_t)arow * HC + kg * 8;
  const unsigned short* wb = WhT + (size_t)r * HC + kg * 8;
  const unsigned short* lb = WlT + (size_t)r * HC + kg * 8;
  f32x4 acc[2];
  acc[0] = f32x4{0.f, 0.f, 0.f, 0.f};
  acc[1] = f32x4{0.f, 0.f, 0.f, 0.f};
  #pragma unroll
  for (int k0 = 0; k0 < HC; k0 += 32) {
    bf16x8 ah = *reinterpret_cast<const bf16x8*>(ah_p + k0);
    bf16x8 al = *reinterpret_cast<const bf16x8*>(al_p + k0);
    #pragma unroll
    for (int c = 0; c < 2; c++) {
      bf16x8 bh = *reinterpret_cast<const bf16x8*>(wb + (size_t)c * 16 * HC + k0);
      bf16x8 bl = *reinterpret_cast<const bf16x8*>(lb + (size_t)c * 16 * HC + k0);
      acc[c] = __builtin_amdgcn_mfma_f32_16x16x32_bf16(ah, bh, acc[c], 0, 0, 0);
      acc[c] = __builtin_amdgcn_mfma_f32_16x16x32_bf16(ah, bl, acc[c], 0, 0, 0);
      acc[c] = __builtin_amdgcn_mfma_f32_16x16x32_bf16(al, bh, acc[c], 0, 0, 0);
    }
  }
  const int crow0 = row0 + kg * 4;
  #pragma unroll
  for (int c = 0; c < 2; c++) {
    const int ccol = c * 16 + r;
    #pragma unroll
    for (int t = 0; t < 4; t++) {
      int rr = crow0 + t;
      if (rr < N_NODES) H[(size_t)rr * OUT_CH + ccol] = acc[c][t];
    }
  }
}

// --- e_src/e_dst per (node, head): dot(h1b[n,h,:], a_src[h,:]) (bf16 h1) ---
__global__ __launch_bounds__(256) void edot1(const unsigned short* __restrict__ h1b,
                                             const float* __restrict__ a_src,
                                             const float* __restrict__ a_dst,
                                             float* __restrict__ es,
                                             float* __restrict__ ed) {
  int idx = blockIdx.x * 256 + threadIdx.x;
  if (idx >= N_NODES * HEADS) return;
  int n = idx / HEADS, h = idx - n * HEADS;
  const uint4* hp = reinterpret_cast<const uint4*>(h1b + (size_t)n * HC + h * OUT_CH);
  const float2* ap = reinterpret_cast<const float2*>(a_src + h * OUT_CH);
  const float2* bp = reinterpret_cast<const float2*>(a_dst + h * OUT_CH);
  float s = 0.f, d = 0.f;
  #pragma unroll
  for (int q = 0; q < 4; q++) {                      // 8 bf16 per uint4
    uint4 u = hp[q];
    unsigned w[4] = {u.x, u.y, u.z, u.w};
    #pragma unroll
    for (int k = 0; k < 4; k++) {
      float lo = bflo(w[k]), hi = bfhi(w[k]);
      float2 av = ap[q * 4 + k], bv = bp[q * 4 + k];
      s += lo * av.x + hi * av.y;
      d += lo * bv.x + hi * bv.y;
    }
  }
  es[idx] = s; ed[idx] = d;
}

// ------ layer-1 aggregation: one wave per dst node, wave-coop softmax ------
// lane covers cols t = lane + 64q (q=0..4); head of (lane,q) = 2q + (lane>>5)
// h1 gathered as bf16 (half traffic); epilogue writes act hi/lo splits.
__global__ __launch_bounds__(256) void agg1(const int* __restrict__ roff,
                                            const int* __restrict__ ssrc,
                                            const float* __restrict__ es,
                                            const float* __restrict__ ed,
                                            const unsigned short* __restrict__ h1b,
                                            const float* __restrict__ b1,
                                            unsigned short* __restrict__ acth,
                                            unsigned short* __restrict__ actl) {
  __shared__ float lds[4][64][11];   // [wave][edge][0..9]=ex, [10]=src bits
  const int n = (blockIdx.x * 256 + threadIdx.x) >> 6;
  if (n >= N_NODES) return;
  const int wslot = threadIdx.x >> 6;
  const int lane = threadIdx.x & 63;
  const int hb = lane >> 5;                 // 0 or 1
  const int beg = roff[n];
  const int deg = roff[n + 1] - beg;

  if (deg == 0) {
    #pragma unroll
    for (int q = 0; q < 5; q++) {
      float v = b1[lane + 64 * q];
      v = v > 0.f ? v : expm1f(v);
      store_split(acth, actl, (size_t)n * HC + lane + 64 * q, v);
    }
    return;
  }

  float acc[5] = {};

  if (deg <= 64) {
    // ---- phase 1: lane e owns edge e; compute 10 alphas in registers ----
    const int active = (lane < deg);
    const int src = ssrc[beg + (active ? lane : 0)];
    float a[10];
    #pragma unroll
    for (int p = 0; p < 5; p++) {
      float2 edp = *reinterpret_cast<const float2*>(ed + n * 10 + 2 * p);
      float2 esp = *reinterpret_cast<const float2*>(es + src * 10 + 2 * p);
      a[2 * p]     = active ? leaky(esp.x + edp.x) : -1e30f;
      a[2 * p + 1] = active ? leaky(esp.y + edp.y) : -1e30f;
    }
    // per-head wave max
    float m[10];
    #pragma unroll
    for (int h = 0; h < 10; h++) m[h] = a[h];
    #pragma unroll
    for (int o = 1; o < 64; o <<= 1)
      #pragma unroll
      for (int h = 0; h < 10; h++) m[h] = fmaxf(m[h], __shfl_xor(m[h], o));
    // exp, park in LDS; per-head wave denom
    float d[10];
    #pragma unroll
    for (int h = 0; h < 10; h++) {
      float ex = expf(a[h] - m[h]);        // 0 for inactive lanes
      lds[wslot][lane][h] = ex;
      d[h] = ex;
    }
    lds[wslot][lane][10] = __int_as_float(src);
    #pragma unroll
    for (int o = 1; o < 64; o <<= 1)
      #pragma unroll
      for (int h = 0; h < 10; h++) d[h] += __shfl_xor(d[h], o);

    // ---- phase 2: gather bf16 h1 rows weighted by LDS-broadcast coefs ----
    int j = 0;
    for (; j + 4 <= deg; j += 4) {
      int s0 = __float_as_int(lds[wslot][j + 0][10]);
      int s1 = __float_as_int(lds[wslot][j + 1][10]);
      int s2 = __float_as_int(lds[wslot][j + 2][10]);
      int s3 = __float_as_int(lds[wslot][j + 3][10]);
      const unsigned short* __restrict__ r0 = h1b + (size_t)s0 * HC + lane;
      const unsigned short* __restrict__ r1 = h1b + (size_t)s1 * HC + lane;
      const unsigned short* __restrict__ r2 = h1b + (size_t)s2 * HC + lane;
      const unsigned short* __restrict__ r3 = h1b + (size_t)s3 * HC + lane;
      float v0[5], v1[5], v2[5], v3[5];
      #pragma unroll
      for (int q = 0; q < 5; q++) v0[q] = bf2f(r0[64 * q]);
      #pragma unroll
      for (int q = 0; q < 5; q++) v1[q] = bf2f(r1[64 * q]);
      #pragma unroll
      for (int q = 0; q < 5; q++) v2[q] = bf2f(r2[64 * q]);
      #pragma unroll
      for (int q = 0; q < 5; q++) v3[q] = bf2f(r3[64 * q]);
      #pragma unroll
      for (int q = 0; q < 5; q++) {
        acc[q] = fmaf(v0[q], lds[wslot][j + 0][2 * q + hb], acc[q]);
        acc[q] = fmaf(v1[q], lds[wslot][j + 1][2 * q + hb], acc[q]);
        acc[q] = fmaf(v2[q], lds[wslot][j + 2][2 * q + hb], acc[q]);
        acc[q] = fmaf(v3[q], lds[wslot][j + 3][2 * q + hb], acc[q]);
      }
    }
    for (; j < deg; j++) {
      int sj = __float_as_int(lds[wslot][j][10]);
      const unsigned short* __restrict__ hrow = h1b + (size_t)sj * HC + lane;
      #pragma unroll
      for (int q = 0; q < 5; q++)
        acc[q] = fmaf(bf2f(hrow[64 * q]), lds[wslot][j][2 * q + hb], acc[q]);
    }
    #pragma unroll
    for (int q = 0; q < 5; q++) {
      float v = acc[q] / (d[2 * q + hb] + 1e-16f) + b1[lane + 64 * q];
      v = v > 0.f ? v : expm1f(v);
      store_split(acth, actl, (size_t)n * HC + lane + 64 * q, v);
    }
  } else {
    // ---- slow fallback (deg > 64): per-lane redundant 2-pass ----
    float edv[5], m2[5];
    #pragma unroll
    for (int q = 0; q < 5; q++) { edv[q] = ed[n * 10 + 2 * q + hb]; m2[q] = -1e30f; }
    for (int j = beg; j < beg + deg; j++) {
      int src = ssrc[j];
      #pragma unroll
      for (int q = 0; q < 5; q++)
        m2[q] = fmaxf(m2[q], leaky(es[src * 10 + 2 * q + hb] + edv[q]));
    }
    float d2[5] = {};
    for (int j = beg; j < beg + deg; j++) {
      int src = ssrc[j];
      const unsigned short* hrow = h1b + (size_t)src * HC + lane;
      #pragma unroll
      for (int q = 0; q < 5; q++) {
        float ex = expf(leaky(es[src * 10 + 2 * q + hb] + edv[q]) - m2[q]);
        acc[q] = fmaf(bf2f(hrow[64 * q]), ex, acc[q]);
        d2[q] += ex;
      }
    }
    #pragma unroll
    for (int q = 0; q < 5; q++) {
      float v = acc[q] / (d2[q] + 1e-16f) + b1[lane + 64 * q];
      v = v > 0.f ? v : expm1f(v);
      store_split(acth, actl, (size_t)n * HC + lane + 64 * q, v);
    }
  }
}

// ---------------- e_src2/e_dst2 per node (H=1) -----------------------------
__global__ __launch_bounds__(256) void edot2(const float* __restrict__ h2,
                                             const float* __restrict__ a_src,
                                             const float* __restrict__ a_dst,
                                             float* __restrict__ es,
                                             float* __restrict__ ed) {
  int n = blockIdx.x * 256 + threadIdx.x;
  if (n >= N_NODES) return;
  const float4* hp = reinterpret_cast<const float4*>(h2 + (size_t)n * OUT_CH);
  const float4* ap = reinterpret_cast<const float4*>(a_src);
  const float4* bp = reinterpret_cast<const float4*>(a_dst);
  float s = 0.f, d = 0.f;
  #pragma unroll
  for (int q = 0; q < 8; q++) {
    float4 hv = hp[q], av = ap[q], dv = bp[q];
    s += hv.x * av.x + hv.y * av.y + hv.z * av.z + hv.w * av.w;
    d += hv.x * dv.x + hv.y * dv.y + hv.z * dv.z + hv.w * dv.w;
  }
  es[n] = s; ed[n] = d;
}

// ------ layer-2 aggregation: one wave per node, unrolled, fused pool -------
__global__ __launch_bounds__(256) void agg2(const int* __restrict__ roff,
                                            const int* __restrict__ ssrc,
                                            const float* __restrict__ es,
                                            const float* __restrict__ ed,
                                            const float* __restrict__ h2,
                                            const float* __restrict__ b2,
                                            const int* __restrict__ batch,
                                            unsigned* __restrict__ pooled) {
  __shared__ float lds[4][64][2];    // [wave][edge][0]=ex, [1]=src bits
  const int n = (blockIdx.x * 256 + threadIdx.x) >> 6;
  if (n >= N_NODES) return;
  const int wslot = threadIdx.x >> 6;
  const int lane = threadIdx.x & 63;
  const int c = lane & 31;
  const int hb = lane >> 5;
  const int beg = roff[n];
  const int deg = roff[n + 1] - beg;
  const int g = batch[n];

  if (deg == 0) {
    if (lane < 32) {
      float v = b2[c];
      v = v > 0.f ? v : expm1f(v);
      atomicMax(&pooled[g * OUT_CH + c], fmap(v));
    }
    return;
  }

  float acc = 0.f, dtot;

  if (deg <= 64) {
    const int active = (lane < deg);
    const int src = ssrc[beg + (active ? lane : 0)];
    const float edv = ed[n];
    float a = active ? leaky(es[src] + edv) : -1e30f;
    float m = a;
    #pragma unroll
    for (int o = 1; o < 64; o <<= 1) m = fmaxf(m, __shfl_xor(m, o));
    float ex = expf(a - m);
    float d = ex;
    #pragma unroll
    for (int o = 1; o < 64; o <<= 1) d += __shfl_xor(d, o);
    dtot = d;
    lds[wslot][lane][0] = ex;
    lds[wslot][lane][1] = __int_as_float(src);
    int j = hb;
    for (; j + 6 < deg; j += 8) {
      int s0 = __float_as_int(lds[wslot][j + 0][1]);
      int s1 = __float_as_int(lds[wslot][j + 2][1]);
      int s2 = __float_as_int(lds[wslot][j + 4][1]);
      int s3 = __float_as_int(lds[wslot][j + 6][1]);
      float c0 = lds[wslot][j + 0][0];
      float c1 = lds[wslot][j + 2][0];
      float c2 = lds[wslot][j + 4][0];
      float c3 = lds[wslot][j + 6][0];
      float v0 = h2[(size_t)s0 * OUT_CH + c];
      float v1 = h2[(size_t)s1 * OUT_CH + c];
      float v2 = h2[(size_t)s2 * OUT_CH + c];
      float v3 = h2[(size_t)s3 * OUT_CH + c];
      acc = fmaf(v0, c0, acc);
      acc = fmaf(v1, c1, acc);
      acc = fmaf(v2, c2, acc);
      acc = fmaf(v3, c3, acc);
    }
    for (; j < deg; j += 2) {
      int sj = __float_as_int(lds[wslot][j][1]);
      acc = fmaf(h2[(size_t)sj * OUT_CH + c], lds[wslot][j][0], acc);
    }
  } else {
    const float edv = ed[n];
    float m = -1e30f;
    for (int j = beg; j < beg + deg; j++)
      m = fmaxf(m, leaky(es[ssrc[j]] + edv));
    float d = 0.f;
    for (int j = beg + hb; j < beg + deg; j += 2) {
      int src = ssrc[j];
      float ex = expf(leaky(es[src] + edv) - m);
      acc = fmaf(h2[(size_t)src * OUT_CH + c], ex, acc);
      d += ex;
    }
    d += __shfl_xor(d, 32);
    dtot = d;
  }

  acc += __shfl_xor(acc, 32);
  if (lane < 32) {
    float v = acc / (dtot + 1e-16f) + b2[c];
    v = v > 0.f ? v : expm1f(v);
    atomicMax(&pooled[g * OUT_CH + c], fmap(v));
  }
}

// -------- final: out[g,c] = relu(pooled[g,:] @ fc_w[:,c] + fc_b[c]) --------
__global__ __launch_bounds__(256) void final_k(const unsigned* __restrict__ pooled,
                                               const float* __restrict__ fc_w,
                                               const float* __restrict__ fc_b,
                                               float* __restrict__ out) {
  int idx = blockIdx.x * 256 + threadIdx.x;
  if (idx >= N_GRAPHS * OUT_CH) return;
  int g = idx >> 5, c = idx & 31;
  float s = fc_b[c];
  #pragma unroll
  for (int k = 0; k < OUT_CH; k++) {
    unsigned u = pooled[g * OUT_CH + k];
    float p = (u == 0u) ? 0.f : funmap(u);
    s += p * fc_w[k * OUT_CH + c];
  }
  out[idx] = s > 0.f ? s : 0.f;
}

extern "C" void kernel_launch(void* const* d_in, const int* in_sizes, int n_in,
                              void* d_out, int out_size, void* d_ws, size_t ws_size,
                              hipStream_t stream) {
  const float* x      = (const float*)d_in[0];
  const int*   ei     = (const int*)d_in[1];
  const int*   batch  = (const int*)d_in[2];
  const float* W1     = (const float*)d_in[4];
  const float* a_src1 = (const float*)d_in[5];
  const float* a_dst1 = (const float*)d_in[6];
  const float* b1     = (const float*)d_in[7];
  const float* W2     = (const float*)d_in[8];
  const float* a_src2 = (const float*)d_in[9];
  const float* a_dst2 = (const float*)d_in[10];
  const float* b2     = (const float*)d_in[11];
  const float* fc_w   = (const float*)d_in[12];
  const float* fc_b   = (const float*)d_in[13];
  float* out = (float*)d_out;

  // ---- workspace layout (<= 136 MB, phase-aliased) ----
  // A [0,64M):   h1b bf16 32MB (gemm1->edot1->agg1); h2 f32 reuses after agg1
  // B [64M,128M): phase1 Xh|Xl (25.6M); phase2 act_h|act_l (64M)
  // S [128M,136M): CSR + es/ed + pooled; W-splits alias dead deg/cursor
  char* ws = (char*)d_ws;
  unsigned short* h1b = (unsigned short*)(ws);              // 32 MB
  float* h2   = (float*)(ws);                               // after agg1
  unsigned short* Xh   = (unsigned short*)(ws + 64000000);  // 12.8 MB
  unsigned short* Xl   = (unsigned short*)(ws + 76800000);  // 12.8 MB
  unsigned short* acth = (unsigned short*)(ws + 64000000);  // 32 MB (after gemm1)
  unsigned short* actl = (unsigned short*)(ws + 96000000);  // 32 MB
  char*  S    = ws + 128000000;
  int*   ssrc   = (int*)(S);                  // 3.2 MB
  int*   roff   = (int*)(S + 3200000);        // 200,004 B
  int*   deg    = (int*)(S + 3400064);        // 200,000 B (dead after scan)
  int*   cursor = (int*)(S + 3600064);        // 200,000 B (dead after scatter)
  unsigned short* W1hT = (unsigned short*)(S + 3400064);            // 81,920 B
  unsigned short* W1lT = (unsigned short*)(S + 3400064 + 81920);    // 81,920 B
  unsigned short* W2hT = (unsigned short*)(S + 3400064 + 163840);   // 20,480 B
  unsigned short* W2lT = (unsigned short*)(S + 3400064 + 184320);   // 20,480 B
  float* es1    = (float*)(S + 3800064);      // 2 MB
  float* ed1    = (float*)(S + 5800064);      // 2 MB
  int*   bsum   = (int*)(S + 7800064);        // 784 B
  unsigned* pooled = (unsigned*)(S + 7801600);// 64 KB
  float* es2 = es1; float* ed2 = ed1;         // dead after agg1

  // ---- CSR build ----
  hipMemsetAsync(deg, 0, (size_t)N_NODES * 4, stream);
  hipMemsetAsync(cursor, 0, (size_t)N_NODES * 4, stream);
  hist_k   <<<(N_EDGES + 255) / 256, 256, 0, stream>>>(ei, deg);
  scan_blk <<<NBLK_SCAN, 256, 0, stream>>>(deg, roff, bsum);
  scan_top <<<1, 256, 0, stream>>>(bsum);
  scan_add <<<NBLK_SCAN, 256, 0, stream>>>(roff, bsum);
  scatter_k<<<(N_EDGES + 255) / 256, 256, 0, stream>>>(ei, roff, cursor, ssrc);

  // ---- bf16 splits (conv_w AFTER scatter: aliases deg/cursor) ----
  conv_x<<<(N_NODES * IN_CH / 4 + 255) / 256, 256, 0, stream>>>(x, Xh, Xl);
  conv_w<<<(IN_CH * HC + OUT_CH * HC + 255) / 256, 256, 0, stream>>>(
      W1, W2, W1hT, W1lT, W2hT, W2lT);

  // ---- layer 1 ----
  gemm1_mfma<<<(N_NODES + 63) / 64, 256, 0, stream>>>(Xh, Xl, W1hT, W1lT, h1b);
  edot1<<<(N_NODES * HEADS + 255) / 256, 256, 0, stream>>>(h1b, a_src1, a_dst1, es1, ed1);
  agg1 <<<(N_NODES * 64 + 255) / 256, 256, 0, stream>>>(roff, ssrc, es1, ed1, h1b, b1,
                                                        acth, actl);

  // ---- layer 2 ----
  hipMemsetAsync(pooled, 0, (size_t)N_GRAPHS * OUT_CH * 4, stream);
  gemm2_mfma<<<(N_NODES + 63) / 64, 256, 0, stream>>>(acth, actl, W2hT, W2lT, h2);
  edot2<<<(N_NODES + 255) / 256, 256, 0, stream>>>(h2, a_src2, a_dst2, es2, ed2);
  agg2 <<<(N_NODES * 64 + 255) / 256, 256, 0, stream>>>(roff, ssrc, es2, ed2, h2, b2,
                                                        batch, pooled);
  final_k<<<(N_GRAPHS * OUT_CH + 255) / 256, 256, 0, stream>>>(pooled, fc_w, fc_b, out);
}

// Round 14
// 375.846 us; speedup vs baseline: 1.2604x; 1.0032x over previous
//
#include <hip/hip_runtime.h>

#define N_NODES 50000
#define N_EDGES 800000
#define IN_CH   128
#define OUT_CH  32
#define HEADS   10
#define HC      320           // HEADS*OUT_CH
#define N_GRAPHS 512
#define NEG_SLOPE 0.2f
#define NBLK_SCAN 196         // ceil(50000/256)

typedef __attribute__((ext_vector_type(8))) short bf16x8;   // 8 bf16 in 4 VGPRs
typedef __attribute__((ext_vector_type(4))) float f32x4;

// ---- order-preserving float<->uint map for atomicMax-based segment_max ----
__device__ __forceinline__ unsigned fmap(float f) {
  unsigned u = __float_as_uint(f);
  return (u & 0x80000000u) ? ~u : (u | 0x80000000u);
}
__device__ __forceinline__ float funmap(unsigned u) {
  u = (u & 0x80000000u) ? (u ^ 0x80000000u) : ~u;
  return __uint_as_float(u);
}
__device__ __forceinline__ float leaky(float a) {
  return a > 0.f ? a : NEG_SLOPE * a;
}
// ---- bf16 helpers (RNE) + hi/lo split store ----
__device__ __forceinline__ unsigned short f2bf(float f) {
  unsigned u = __float_as_uint(f);
  return (unsigned short)((u + 0x7FFFu + ((u >> 16) & 1u)) >> 16);
}
__device__ __forceinline__ float bf2f(unsigned short b) {
  return __uint_as_float(((unsigned)b) << 16);
}
// packed-pair unpack: uint holds bf16 c=2i (low16) and c=2i+1 (high16)
__device__ __forceinline__ float bflo(unsigned u) { return __uint_as_float(u << 16); }
__device__ __forceinline__ float bfhi(unsigned u) { return __uint_as_float(u & 0xFFFF0000u); }
__device__ __forceinline__ void store_split(unsigned short* __restrict__ ph,
                                            unsigned short* __restrict__ pl,
                                            size_t idx, float v) {
  unsigned short h = f2bf(v);
  ph[idx] = h;
  pl[idx] = f2bf(v - bf2f(h));
}
__device__ __forceinline__ float elu(float v) {
  return v > 0.f ? v : expm1f(v);
}

// ============================ CSR construction =============================
__global__ __launch_bounds__(256) void hist_k(const int* __restrict__ ei,
                                              int* __restrict__ deg) {
  int e = blockIdx.x * 256 + threadIdx.x;
  if (e < N_EDGES) atomicAdd(&deg[ei[N_EDGES + e]], 1);
}

__global__ __launch_bounds__(256) void scan_blk(const int* __restrict__ deg,
                                                int* __restrict__ roff,
                                                int* __restrict__ bsum) {
  __shared__ int s[256];
  int i = blockIdx.x * 256 + threadIdx.x;
  int v = (i < N_NODES) ? deg[i] : 0;
  s[threadIdx.x] = v;
  __syncthreads();
  #pragma unroll
  for (int o = 1; o < 256; o <<= 1) {
    int t = (threadIdx.x >= o) ? s[threadIdx.x - o] : 0;
    __syncthreads();
    s[threadIdx.x] += t;
    __syncthreads();
  }
  if (i < N_NODES) roff[i] = s[threadIdx.x] - v;   // exclusive
  if (threadIdx.x == 255) bsum[blockIdx.x] = s[255];
}

__global__ __launch_bounds__(256) void scan_top(int* __restrict__ bsum) {
  __shared__ int s[256];
  int i = threadIdx.x;
  int v = (i < NBLK_SCAN) ? bsum[i] : 0;
  s[i] = v;
  __syncthreads();
  #pragma unroll
  for (int o = 1; o < 256; o <<= 1) {
    int t = (i >= o) ? s[i - o] : 0;
    __syncthreads();
    s[i] += t;
    __syncthreads();
  }
  if (i < NBLK_SCAN) bsum[i] = s[i] - v;           // exclusive
}

__global__ __launch_bounds__(256) void scan_add(int* __restrict__ roff,
                                                const int* __restrict__ bsum) {
  int i = blockIdx.x * 256 + threadIdx.x;
  if (i < N_NODES) roff[i] += bsum[blockIdx.x];
  if (i == 0) roff[N_NODES] = N_EDGES;
}

__global__ __launch_bounds__(256) void scatter_k(const int* __restrict__ ei,
                                                 const int* __restrict__ roff,
                                                 int* __restrict__ cursor,
                                                 int* __restrict__ ssrc) {
  int e = blockIdx.x * 256 + threadIdx.x;
  if (e >= N_EDGES) return;
  int dst = ei[N_EDGES + e];
  int pos = roff[dst] + atomicAdd(&cursor[dst], 1);
  ssrc[pos] = ei[e];
}

// =================== bf16 hi/lo conversions for MFMA GEMMs =================
__global__ __launch_bounds__(256) void conv_x(const float* __restrict__ X,
                                              unsigned short* __restrict__ Xh,
                                              unsigned short* __restrict__ Xl) {
  int i = blockIdx.x * 256 + threadIdx.x;          // float4 index
  if (i >= N_NODES * IN_CH / 4) return;
  float4 v = reinterpret_cast<const float4*>(X)[i];
  ushort4 h, l;
  h.x = f2bf(v.x); l.x = f2bf(v.x - bf2f(h.x));
  h.y = f2bf(v.y); l.y = f2bf(v.y - bf2f(h.y));
  h.z = f2bf(v.z); l.z = f2bf(v.z - bf2f(h.z));
  h.w = f2bf(v.w); l.w = f2bf(v.w - bf2f(h.w));
  reinterpret_cast<ushort4*>(Xh)[i] = h;
  reinterpret_cast<ushort4*>(Xl)[i] = l;
}

// W1[128][320] -> W1T[320][128] hi/lo ; W2[320][32] -> W2T[32][320] hi/lo
__global__ __launch_bounds__(256) void conv_w(const float* __restrict__ W1,
                                              const float* __restrict__ W2,
                                              unsigned short* __restrict__ W1hT,
                                              unsigned short* __restrict__ W1lT,
                                              unsigned short* __restrict__ W2hT,
                                              unsigned short* __restrict__ W2lT) {
  int i = blockIdx.x * 256 + threadIdx.x;
  if (i < IN_CH * HC) {                 // i = n*128 + k
    int n = i >> 7, k = i & 127;
    float v = W1[(size_t)k * HC + n];
    unsigned short h = f2bf(v);
    W1hT[i] = h; W1lT[i] = f2bf(v - bf2f(h));
  } else {
    int j = i - IN_CH * HC;
    if (j < OUT_CH * HC) {              // j = c*320 + k
      int c = j / HC, k = j - c * HC;
      float v = W2[(size_t)k * OUT_CH + c];
      unsigned short h = f2bf(v);
      W2hT[j] = h; W2lT[j] = f2bf(v - bf2f(h));
    }
  }
}

// ======== GEMM1 via MFMA split-bf16: h1b[N,320](bf16) = X @ W1 =============
// block = 64-row x 320-col strip; wave = 16 rows x 20 col-tiles.
// C/D: col=lane&15, row=(lane>>4)*4+reg  [verified m89]
__global__ __launch_bounds__(256) void gemm1_mfma(const unsigned short* __restrict__ Xh,
                                                  const unsigned short* __restrict__ Xl,
                                                  const unsigned short* __restrict__ WhT,
                                                  const unsigned short* __restrict__ WlT,
                                                  unsigned short* __restrict__ Hb) {
  const int wave = threadIdx.x >> 6;
  const int lane = threadIdx.x & 63;
  const int row0 = blockIdx.x * 64 + wave * 16;
  const int r = lane & 15;
  const int kg = lane >> 4;                          // 0..3
  int arow = row0 + r; if (arow >= N_NODES) arow = N_NODES - 1;
  const unsigned short* xh = Xh + (size_t)arow * IN_CH + kg * 8;
  const unsigned short* xl = Xl + (size_t)arow * IN_CH + kg * 8;
  const unsigned short* wb = WhT + (size_t)r * IN_CH + kg * 8;   // col-tile 0
  const unsigned short* lb = WlT + (size_t)r * IN_CH + kg * 8;
  f32x4 acc[20];
  #pragma unroll
  for (int c = 0; c < 20; c++) acc[c] = f32x4{0.f, 0.f, 0.f, 0.f};
  #pragma unroll
  for (int k0 = 0; k0 < IN_CH; k0 += 32) {
    bf16x8 ah = *reinterpret_cast<const bf16x8*>(xh + k0);
    bf16x8 al = *reinterpret_cast<const bf16x8*>(xl + k0);
    #pragma unroll
    for (int c = 0; c < 20; c++) {
      bf16x8 bh = *reinterpret_cast<const bf16x8*>(wb + (size_t)c * 16 * IN_CH + k0);
      bf16x8 bl = *reinterpret_cast<const bf16x8*>(lb + (size_t)c * 16 * IN_CH + k0);
      acc[c] = __builtin_amdgcn_mfma_f32_16x16x32_bf16(ah, bh, acc[c], 0, 0, 0);
      acc[c] = __builtin_amdgcn_mfma_f32_16x16x32_bf16(ah, bl, acc[c], 0, 0, 0);
      acc[c] = __builtin_amdgcn_mfma_f32_16x16x32_bf16(al, bh, acc[c], 0, 0, 0);
    }
  }
  const int crow0 = row0 + kg * 4;
  #pragma unroll
  for (int c = 0; c < 20; c++) {
    const int ccol = c * 16 + r;
    #pragma unroll
    for (int t = 0; t < 4; t++) {
      int rr = crow0 + t;
      if (rr < N_NODES) Hb[(size_t)rr * HC + ccol] = f2bf(acc[c][t]);
    }
  }
}

// ======== GEMM2 via MFMA split-bf16: h2[N,32](f32) = act @ W2 ==============
__global__ __launch_bounds__(256) void gemm2_mfma(const unsigned short* __restrict__ Ah,
                                                  const unsigned short* __restrict__ Al,
                                                  const unsigned short* __restrict__ WhT,
                                                  const unsigned short* __restrict__ WlT,
                                                  float* __restrict__ H) {
  const int wave = threadIdx.x >> 6;
  const int lane = threadIdx.x & 63;
  const int row0 = blockIdx.x * 64 + wave * 16;
  const int r = lane & 15;
  const int kg = lane >> 4;
  int arow = row0 + r; if (arow >= N_NODES) arow = N_NODES - 1;
  const unsigned short* ah_p = Ah + (size_t)arow * HC + kg * 8;
  const unsigned short* al_p = Al + (size_t)arow * HC + kg * 8;
  const unsigned short* wb = WhT + (size_t)r * HC + kg * 8;
  const unsigned short* lb = WlT + (size_t)r * HC + kg * 8;
  f32x4 acc[2];
  acc[0] = f32x4{0.f, 0.f, 0.f, 0.f};
  acc[1] = f32x4{0.f, 0.f, 0.f, 0.f};
  #pragma unroll
  for (int k0 = 0; k0 < HC; k0 += 32) {
    bf16x8 ah = *reinterpret_cast<const bf16x8*>(ah_p + k0);
    bf16x8 al = *reinterpret_cast<const bf16x8*>(al_p + k0);
    #pragma unroll
    for (int c = 0; c < 2; c++) {
      bf16x8 bh = *reinterpret_cast<const bf16x8*>(wb + (size_t)c * 16 * HC + k0);
      bf16x8 bl = *reinterpret_cast<const bf16x8*>(lb + (size_t)c * 16 * HC + k0);
      acc[c] = __builtin_amdgcn_mfma_f32_16x16x32_bf16(ah, bh, acc[c], 0, 0, 0);
      acc[c] = __builtin_amdgcn_mfma_f32_16x16x32_bf16(ah, bl, acc[c], 0, 0, 0);
      acc[c] = __builtin_amdgcn_mfma_f32_16x16x32_bf16(al, bh, acc[c], 0, 0, 0);
    }
  }
  const int crow0 = row0 + kg * 4;
  #pragma unroll
  for (int c = 0; c < 2; c++) {
    const int ccol = c * 16 + r;
    #pragma unroll
    for (int t = 0; t < 4; t++) {
      int rr = crow0 + t;
      if (rr < N_NODES) H[(size_t)rr * OUT_CH + ccol] = acc[c][t];
    }
  }
}

// --- e_src/e_dst per (node, head): dot(h1b[n,h,:], a_src[h,:]) (bf16 h1) ---
__global__ __launch_bounds__(256) void edot1(const unsigned short* __restrict__ h1b,
                                             const float* __restrict__ a_src,
                                             const float* __restrict__ a_dst,
                                             float* __restrict__ es,
                                             float* __restrict__ ed) {
  int idx = blockIdx.x * 256 + threadIdx.x;
  if (idx >= N_NODES * HEADS) return;
  int n = idx / HEADS, h = idx - n * HEADS;
  const uint4* hp = reinterpret_cast<const uint4*>(h1b + (size_t)n * HC + h * OUT_CH);
  const float2* ap = reinterpret_cast<const float2*>(a_src + h * OUT_CH);
  const float2* bp = reinterpret_cast<const float2*>(a_dst + h * OUT_CH);
  float s = 0.f, d = 0.f;
  #pragma unroll
  for (int q = 0; q < 4; q++) {                      // 8 bf16 per uint4
    uint4 u = hp[q];
    unsigned w[4] = {u.x, u.y, u.z, u.w};
    #pragma unroll
    for (int k = 0; k < 4; k++) {
      float lo = bflo(w[k]), hi = bfhi(w[k]);
      float2 av = ap[q * 4 + k], bv = bp[q * 4 + k];
      s += lo * av.x + hi * av.y;
      d += lo * bv.x + hi * bv.y;
    }
  }
  es[idx] = s; ed[idx] = d;
}

// ------ layer-1 aggregation: one wave per dst node, wave-coop softmax ------
// Phase 1 (no max-shift; softmax shift-invariant, alpha ~ [-3,3]):
//   lane e owns edge e; ex[10] -> LDS; denom via shfl reduce.
// Phase 2: 2 edges/iter. half=lane>>5 picks edge j+half; lc=lane&31.
//   main: uint4 load = cols 8lc..8lc+7 (head lc>>2, one coef).
//   tail: uint load = cols 256+2lc..+1 (head 8+(lc>>4)).
//   Accumulators merged lane<->lane+32 via shfl_xor(32); lanes<32 write.
__global__ __launch_bounds__(256) void agg1(const int* __restrict__ roff,
                                            const int* __restrict__ ssrc,
                                            const float* __restrict__ es,
                                            const float* __restrict__ ed,
                                            const unsigned short* __restrict__ h1b,
                                            const float* __restrict__ b1,
                                            unsigned short* __restrict__ acth,
                                            unsigned short* __restrict__ actl) {
  __shared__ float lds[4][64][11];   // [wave][edge][0..9]=ex, [10]=src bits
  const int n = (blockIdx.x * 256 + threadIdx.x) >> 6;
  if (n >= N_NODES) return;
  const int wslot = threadIdx.x >> 6;
  const int lane = threadIdx.x & 63;
  const int beg = roff[n];
  const int deg = roff[n + 1] - beg;

  if (deg == 0) {
    #pragma unroll
    for (int q = 0; q < 5; q++) {
      float v = elu(b1[lane + 64 * q]);
      store_split(acth, actl, (size_t)n * HC + lane + 64 * q, v);
    }
    return;
  }

  if (deg <= 64) {
    // ---- phase 1: lane e owns edge e; ex = exp(leaky(alpha)) (no shift) ---
    const int active = (lane < deg);
    const int src = ssrc[beg + (active ? lane : 0)];
    float d[10];
    #pragma unroll
    for (int p = 0; p < 5; p++) {
      float2 edp = *reinterpret_cast<const float2*>(ed + n * 10 + 2 * p);
      float2 esp = *reinterpret_cast<const float2*>(es + src * 10 + 2 * p);
      float e0 = active ? expf(leaky(esp.x + edp.x)) : 0.f;
      float e1 = active ? expf(leaky(esp.y + edp.y)) : 0.f;
      lds[wslot][lane][2 * p] = e0;
      lds[wslot][lane][2 * p + 1] = e1;
      d[2 * p] = e0; d[2 * p + 1] = e1;
    }
    lds[wslot][lane][10] = __int_as_float(src);
    #pragma unroll
    for (int o = 1; o < 64; o <<= 1)
      #pragma unroll
      for (int h = 0; h < 10; h++) d[h] += __shfl_xor(d[h], o);

    // ---- phase 2: 2 edges per iter, uint4 main + uint tail gather ----
    const int half = lane >> 5;
    const int lc = lane & 31;
    const int hm = lc >> 2;            // head of main cols 8lc..8lc+7
    const int ht = 8 + (lc >> 4);      // head of tail cols 256+2lc..+1
    float accm[8] = {};
    float acct0 = 0.f, acct1 = 0.f;
    const int dege = (deg + 1) & ~1;   // edges >= deg have ex=0, valid src
    for (int j = 0; j < dege; j += 2) {
      const int e = j + half;
      int sj = __float_as_int(lds[wslot][e][10]);
      float cm = lds[wslot][e][hm];
      float ct = lds[wslot][e][ht];
      const unsigned short* __restrict__ row = h1b + (size_t)sj * HC;
      uint4 v = *reinterpret_cast<const uint4*>(row + 8 * lc);
      unsigned t = *reinterpret_cast<const unsigned*>(row + 256 + 2 * lc);
      unsigned w0 = v.x, w1 = v.y, w2 = v.z, w3 = v.w;
      accm[0] = fmaf(bflo(w0), cm, accm[0]);
      accm[1] = fmaf(bfhi(w0), cm, accm[1]);
      accm[2] = fmaf(bflo(w1), cm, accm[2]);
      accm[3] = fmaf(bfhi(w1), cm, accm[3]);
      accm[4] = fmaf(bflo(w2), cm, accm[4]);
      accm[5] = fmaf(bfhi(w2), cm, accm[5]);
      accm[6] = fmaf(bflo(w3), cm, accm[6]);
      accm[7] = fmaf(bfhi(w3), cm, accm[7]);
      acct0 = fmaf(bflo(t), ct, acct0);
      acct1 = fmaf(bfhi(t), ct, acct1);
    }
    // merge halves
    #pragma unroll
    for (int k = 0; k < 8; k++) accm[k] += __shfl_xor(accm[k], 32);
    acct0 += __shfl_xor(acct0, 32);
    acct1 += __shfl_xor(acct1, 32);

    if (lane < 32) {
      const float invm = 1.f / (d[hm] + 1e-16f);
      const size_t base = (size_t)n * HC;
      ushort4 sh0, sl0, sh1, sl1;
      float vv;
      unsigned short hh;
      vv = elu(accm[0] * invm + b1[8 * lc + 0]); hh = f2bf(vv); sh0.x = hh; sl0.x = f2bf(vv - bf2f(hh));
      vv = elu(accm[1] * invm + b1[8 * lc + 1]); hh = f2bf(vv); sh0.y = hh; sl0.y = f2bf(vv - bf2f(hh));
      vv = elu(accm[2] * invm + b1[8 * lc + 2]); hh = f2bf(vv); sh0.z = hh; sl0.z = f2bf(vv - bf2f(hh));
      vv = elu(accm[3] * invm + b1[8 * lc + 3]); hh = f2bf(vv); sh0.w = hh; sl0.w = f2bf(vv - bf2f(hh));
      vv = elu(accm[4] * invm + b1[8 * lc + 4]); hh = f2bf(vv); sh1.x = hh; sl1.x = f2bf(vv - bf2f(hh));
      vv = elu(accm[5] * invm + b1[8 * lc + 5]); hh = f2bf(vv); sh1.y = hh; sl1.y = f2bf(vv - bf2f(hh));
      vv = elu(accm[6] * invm + b1[8 * lc + 6]); hh = f2bf(vv); sh1.z = hh; sl1.z = f2bf(vv - bf2f(hh));
      vv = elu(accm[7] * invm + b1[8 * lc + 7]); hh = f2bf(vv); sh1.w = hh; sl1.w = f2bf(vv - bf2f(hh));
      *reinterpret_cast<ushort4*>(acth + base + 8 * lc) = sh0;
      *reinterpret_cast<ushort4*>(acth + base + 8 * lc + 4) = sh1;
      *reinterpret_cast<ushort4*>(actl + base + 8 * lc) = sl0;
      *reinterpret_cast<ushort4*>(actl + base + 8 * lc + 4) = sl1;
      const float invt = 1.f / (d[ht] + 1e-16f);
      ushort2 th, tl;
      vv = elu(acct0 * invt + b1[256 + 2 * lc + 0]); hh = f2bf(vv); th.x = hh; tl.x = f2bf(vv - bf2f(hh));
      vv = elu(acct1 * invt + b1[256 + 2 * lc + 1]); hh = f2bf(vv); th.y = hh; tl.y = f2bf(vv - bf2f(hh));
      *reinterpret_cast<ushort2*>(acth + base + 256 + 2 * lc) = th;
      *reinterpret_cast<ushort2*>(actl + base + 256 + 2 * lc) = tl;
    }
  } else {
    // ---- slow fallback (deg > 64): per-lane redundant 2-pass ----
    const int hb = lane >> 5;
    float acc[5] = {};
    float edv[5], m2[5];
    #pragma unroll
    for (int q = 0; q < 5; q++) { edv[q] = ed[n * 10 + 2 * q + hb]; m2[q] = -1e30f; }
    for (int j = beg; j < beg + deg; j++) {
      int src = ssrc[j];
      #pragma unroll
      for (int q = 0; q < 5; q++)
        m2[q] = fmaxf(m2[q], leaky(es[src * 10 + 2 * q + hb] + edv[q]));
    }
    float d2[5] = {};
    for (int j = beg; j < beg + deg; j++) {
      int src = ssrc[j];
      const unsigned short* hrow = h1b + (size_t)src * HC + lane;
      #pragma unroll
      for (int q = 0; q < 5; q++) {
        float ex = expf(leaky(es[src * 10 + 2 * q + hb] + edv[q]) - m2[q]);
        acc[q] = fmaf(bf2f(hrow[64 * q]), ex, acc[q]);
        d2[q] += ex;
      }
    }
    #pragma unroll
    for (int q = 0; q < 5; q++) {
      float v = elu(acc[q] / (d2[q] + 1e-16f) + b1[lane + 64 * q]);
      store_split(acth, actl, (size_t)n * HC + lane + 64 * q, v);
    }
  }
}

// ---------------- e_src2/e_dst2 per node (H=1) -----------------------------
__global__ __launch_bounds__(256) void edot2(const float* __restrict__ h2,
                                             const float* __restrict__ a_src,
                                             const float* __restrict__ a_dst,
                                             float* __restrict__ es,
                                             float* __restrict__ ed) {
  int n = blockIdx.x * 256 + threadIdx.x;
  if (n >= N_NODES) return;
  const float4* hp = reinterpret_cast<const float4*>(h2 + (size_t)n * OUT_CH);
  const float4* ap = reinterpret_cast<const float4*>(a_src);
  const float4* bp = reinterpret_cast<const float4*>(a_dst);
  float s = 0.f, d = 0.f;
  #pragma unroll
  for (int q = 0; q < 8; q++) {
    float4 hv = hp[q], av = ap[q], dv = bp[q];
    s += hv.x * av.x + hv.y * av.y + hv.z * av.z + hv.w * av.w;
    d += hv.x * dv.x + hv.y * dv.y + hv.z * dv.z + hv.w * dv.w;
  }
  es[n] = s; ed[n] = d;
}

// ------ layer-2 aggregation: one wave per node, unrolled, fused pool -------
__global__ __launch_bounds__(256) void agg2(const int* __restrict__ roff,
                                            const int* __restrict__ ssrc,
                                            const float* __restrict__ es,
                                            const float* __restrict__ ed,
                                            const float* __restrict__ h2,
                                            const float* __restrict__ b2,
                                            const int* __restrict__ batch,
                                            unsigned* __restrict__ pooled) {
  __shared__ float lds[4][64][2];    // [wave][edge][0]=ex, [1]=src bits
  const int n = (blockIdx.x * 256 + threadIdx.x) >> 6;
  if (n >= N_NODES) return;
  const int wslot = threadIdx.x >> 6;
  const int lane = threadIdx.x & 63;
  const int c = lane & 31;
  const int hb = lane >> 5;
  const int beg = roff[n];
  const int deg = roff[n + 1] - beg;
  const int g = batch[n];

  if (deg == 0) {
    if (lane < 32) {
      float v = elu(b2[c]);
      atomicMax(&pooled[g * OUT_CH + c], fmap(v));
    }
    return;
  }

  float acc = 0.f, dtot;

  if (deg <= 64) {
    const int active = (lane < deg);
    const int src = ssrc[beg + (active ? lane : 0)];
    const float edv = ed[n];
    float a = active ? leaky(es[src] + edv) : -1e30f;
    float m = a;
    #pragma unroll
    for (int o = 1; o < 64; o <<= 1) m = fmaxf(m, __shfl_xor(m, o));
    float ex = expf(a - m);
    float d = ex;
    #pragma unroll
    for (int o = 1; o < 64; o <<= 1) d += __shfl_xor(d, o);
    dtot = d;
    lds[wslot][lane][0] = ex;
    lds[wslot][lane][1] = __int_as_float(src);
    int j = hb;
    for (; j + 6 < deg; j += 8) {
      int s0 = __float_as_int(lds[wslot][j + 0][1]);
      int s1 = __float_as_int(lds[wslot][j + 2][1]);
      int s2 = __float_as_int(lds[wslot][j + 4][1]);
      int s3 = __float_as_int(lds[wslot][j + 6][1]);
      float c0 = lds[wslot][j + 0][0];
      float c1 = lds[wslot][j + 2][0];
      float c2 = lds[wslot][j + 4][0];
      float c3 = lds[wslot][j + 6][0];
      float v0 = h2[(size_t)s0 * OUT_CH + c];
      float v1 = h2[(size_t)s1 * OUT_CH + c];
      float v2 = h2[(size_t)s2 * OUT_CH + c];
      float v3 = h2[(size_t)s3 * OUT_CH + c];
      acc = fmaf(v0, c0, acc);
      acc = fmaf(v1, c1, acc);
      acc = fmaf(v2, c2, acc);
      acc = fmaf(v3, c3, acc);
    }
    for (; j < deg; j += 2) {
      int sj = __float_as_int(lds[wslot][j][1]);
      acc = fmaf(h2[(size_t)sj * OUT_CH + c], lds[wslot][j][0], acc);
    }
  } else {
    const float edv = ed[n];
    float m = -1e30f;
    for (int j = beg; j < beg + deg; j++)
      m = fmaxf(m, leaky(es[ssrc[j]] + edv));
    float d = 0.f;
    for (int j = beg + hb; j < beg + deg; j += 2) {
      int src = ssrc[j];
      float ex = expf(leaky(es[src] + edv) - m);
      acc = fmaf(h2[(size_t)src * OUT_CH + c], ex, acc);
      d += ex;
    }
    d += __shfl_xor(d, 32);
    dtot = d;
  }

  acc += __shfl_xor(acc, 32);
  if (lane < 32) {
    float v = elu(acc / (dtot + 1e-16f) + b2[c]);
    atomicMax(&pooled[g * OUT_CH + c], fmap(v));
  }
}

// -------- final: out[g,c] = relu(pooled[g,:] @ fc_w[:,c] + fc_b[c]) --------
__global__ __launch_bounds__(256) void final_k(const unsigned* __restrict__ pooled,
                                               const float* __restrict__ fc_w,
                                               const float* __restrict__ fc_b,
                                               float* __restrict__ out) {
  int idx = blockIdx.x * 256 + threadIdx.x;
  if (idx >= N_GRAPHS * OUT_CH) return;
  int g = idx >> 5, c = idx & 31;
  float s = fc_b[c];
  #pragma unroll
  for (int k = 0; k < OUT_CH; k++) {
    unsigned u = pooled[g * OUT_CH + k];
    float p = (u == 0u) ? 0.f : funmap(u);
    s += p * fc_w[k * OUT_CH + c];
  }
  out[idx] = s > 0.f ? s : 0.f;
}

extern "C" void kernel_launch(void* const* d_in, const int* in_sizes, int n_in,
                              void* d_out, int out_size, void* d_ws, size_t ws_size,
                              hipStream_t stream) {
  const float* x      = (const float*)d_in[0];
  const int*   ei     = (const int*)d_in[1];
  const int*   batch  = (const int*)d_in[2];
  const float* W1     = (const float*)d_in[4];
  const float* a_src1 = (const float*)d_in[5];
  const float* a_dst1 = (const float*)d_in[6];
  const float* b1     = (const float*)d_in[7];
  const float* W2     = (const float*)d_in[8];
  const float* a_src2 = (const float*)d_in[9];
  const float* a_dst2 = (const float*)d_in[10];
  const float* b2     = (const float*)d_in[11];
  const float* fc_w   = (const float*)d_in[12];
  const float* fc_b   = (const float*)d_in[13];
  float* out = (float*)d_out;

  // ---- workspace layout (<= 136 MB, phase-aliased) ----
  char* ws = (char*)d_ws;
  unsigned short* h1b = (unsigned short*)(ws);              // 32 MB
  float* h2   = (float*)(ws);                               // after agg1
  unsigned short* Xh   = (unsigned short*)(ws + 64000000);  // 12.8 MB
  unsigned short* Xl   = (unsigned short*)(ws + 76800000);  // 12.8 MB
  unsigned short* acth = (unsigned short*)(ws + 64000000);  // 32 MB (after gemm1)
  unsigned short* actl = (unsigned short*)(ws + 96000000);  // 32 MB
  char*  S    = ws + 128000000;
  int*   ssrc   = (int*)(S);                  // 3.2 MB
  int*   roff   = (int*)(S + 3200000);        // 200,004 B
  int*   deg    = (int*)(S + 3400064);        // 200,000 B (dead after scan)
  int*   cursor = (int*)(S + 3600064);        // 200,000 B (dead after scatter)
  unsigned short* W1hT = (unsigned short*)(S + 3400064);            // 81,920 B
  unsigned short* W1lT = (unsigned short*)(S + 3400064 + 81920);    // 81,920 B
  unsigned short* W2hT = (unsigned short*)(S + 3400064 + 163840);   // 20,480 B
  unsigned short* W2lT = (unsigned short*)(S + 3400064 + 184320);   // 20,480 B
  float* es1    = (float*)(S + 3800064);      // 2 MB
  float* ed1    = (float*)(S + 5800064);      // 2 MB
  int*   bsum   = (int*)(S + 7800064);        // 784 B
  unsigned* pooled = (unsigned*)(S + 7801600);// 64 KB
  float* es2 = es1; float* ed2 = ed1;         // dead after agg1

  // ---- CSR build ----
  hipMemsetAsync(deg, 0, (size_t)N_NODES * 4, stream);
  hipMemsetAsync(cursor, 0, (size_t)N_NODES * 4, stream);
  hist_k   <<<(N_EDGES + 255) / 256, 256, 0, stream>>>(ei, deg);
  scan_blk <<<NBLK_SCAN, 256, 0, stream>>>(deg, roff, bsum);
  scan_top <<<1, 256, 0, stream>>>(bsum);
  scan_add <<<NBLK_SCAN, 256, 0, stream>>>(roff, bsum);
  scatter_k<<<(N_EDGES + 255) / 256, 256, 0, stream>>>(ei, roff, cursor, ssrc);

  // ---- bf16 splits (conv_w AFTER scatter: aliases deg/cursor) ----
  conv_x<<<(N_NODES * IN_CH / 4 + 255) / 256, 256, 0, stream>>>(x, Xh, Xl);
  conv_w<<<(IN_CH * HC + OUT_CH * HC + 255) / 256, 256, 0, stream>>>(
      W1, W2, W1hT, W1lT, W2hT, W2lT);

  // ---- layer 1 ----
  gemm1_mfma<<<(N_NODES + 63) / 64, 256, 0, stream>>>(Xh, Xl, W1hT, W1lT, h1b);
  edot1<<<(N_NODES * HEADS + 255) / 256, 256, 0, stream>>>(h1b, a_src1, a_dst1, es1, ed1);
  agg1 <<<(N_NODES * 64 + 255) / 256, 256, 0, stream>>>(roff, ssrc, es1, ed1, h1b, b1,
                                                        acth, actl);

  // ---- layer 2 ----
  hipMemsetAsync(pooled, 0, (size_t)N_GRAPHS * OUT_CH * 4, stream);
  gemm2_mfma<<<(N_NODES + 63) / 64, 256, 0, stream>>>(acth, actl, W2hT, W2lT, h2);
  edot2<<<(N_NODES + 255) / 256, 256, 0, stream>>>(h2, a_src2, a_dst2, es2, ed2);
  agg2 <<<(N_NODES * 64 + 255) / 256, 256, 0, stream>>>(roff, ssrc, es2, ed2, h2, b2,
                                                        batch, pooled);
  final_k<<<(N_GRAPHS * OUT_CH + 255) / 256, 256, 0, stream>>>(pooled, fc_w, fc_b, out);
}

// Round 15
// 360.935 us; speedup vs baseline: 1.3125x; 1.0413x over previous
//
#include <hip/hip_runtime.h>

#define N_NODES 50000
#define N_EDGES 800000
#define IN_CH   128
#define OUT_CH  32
#define HEADS   10
#define HC      320           // HEADS*OUT_CH
#define N_GRAPHS 512
#define NEG_SLOPE 0.2f
#define NBLK_SCAN 196         // ceil(50000/256)

typedef __attribute__((ext_vector_type(8))) short bf16x8;   // 8 bf16 in 4 VGPRs
typedef __attribute__((ext_vector_type(4))) float f32x4;

// ---- order-preserving float<->uint map for atomicMax-based segment_max ----
__device__ __forceinline__ unsigned fmap(float f) {
  unsigned u = __float_as_uint(f);
  return (u & 0x80000000u) ? ~u : (u | 0x80000000u);
}
__device__ __forceinline__ float funmap(unsigned u) {
  u = (u & 0x80000000u) ? (u ^ 0x80000000u) : ~u;
  return __uint_as_float(u);
}
__device__ __forceinline__ float leaky(float a) {
  return a > 0.f ? a : NEG_SLOPE * a;
}
// ---- bf16 helpers (RNE) + hi/lo split store ----
__device__ __forceinline__ unsigned short f2bf(float f) {
  unsigned u = __float_as_uint(f);
  return (unsigned short)((u + 0x7FFFu + ((u >> 16) & 1u)) >> 16);
}
__device__ __forceinline__ float bf2f(unsigned short b) {
  return __uint_as_float(((unsigned)b) << 16);
}
// packed-pair unpack: uint holds bf16 c=2i (low16) and c=2i+1 (high16)
__device__ __forceinline__ float bflo(unsigned u) { return __uint_as_float(u << 16); }
__device__ __forceinline__ float bfhi(unsigned u) { return __uint_as_float(u & 0xFFFF0000u); }
__device__ __forceinline__ void store_split(unsigned short* __restrict__ ph,
                                            unsigned short* __restrict__ pl,
                                            size_t idx, float v) {
  unsigned short h = f2bf(v);
  ph[idx] = h;
  pl[idx] = f2bf(v - bf2f(h));
}
__device__ __forceinline__ float elu(float v) {
  return v > 0.f ? v : expm1f(v);
}

// ============================ CSR construction =============================
__global__ __launch_bounds__(256) void hist_k(const int* __restrict__ ei,
                                              int* __restrict__ deg) {
  int e = blockIdx.x * 256 + threadIdx.x;
  if (e < N_EDGES) atomicAdd(&deg[ei[N_EDGES + e]], 1);
}

__global__ __launch_bounds__(256) void scan_blk(const int* __restrict__ deg,
                                                int* __restrict__ roff,
                                                int* __restrict__ bsum) {
  __shared__ int s[256];
  int i = blockIdx.x * 256 + threadIdx.x;
  int v = (i < N_NODES) ? deg[i] : 0;
  s[threadIdx.x] = v;
  __syncthreads();
  #pragma unroll
  for (int o = 1; o < 256; o <<= 1) {
    int t = (threadIdx.x >= o) ? s[threadIdx.x - o] : 0;
    __syncthreads();
    s[threadIdx.x] += t;
    __syncthreads();
  }
  if (i < N_NODES) roff[i] = s[threadIdx.x] - v;   // exclusive
  if (threadIdx.x == 255) bsum[blockIdx.x] = s[255];
}

__global__ __launch_bounds__(256) void scan_top(int* __restrict__ bsum) {
  __shared__ int s[256];
  int i = threadIdx.x;
  int v = (i < NBLK_SCAN) ? bsum[i] : 0;
  s[i] = v;
  __syncthreads();
  #pragma unroll
  for (int o = 1; o < 256; o <<= 1) {
    int t = (i >= o) ? s[i - o] : 0;
    __syncthreads();
    s[i] += t;
    __syncthreads();
  }
  if (i < NBLK_SCAN) bsum[i] = s[i] - v;           // exclusive
}

__global__ __launch_bounds__(256) void scan_add(int* __restrict__ roff,
                                                const int* __restrict__ bsum) {
  int i = blockIdx.x * 256 + threadIdx.x;
  if (i < N_NODES) roff[i] += bsum[blockIdx.x];
  if (i == 0) roff[N_NODES] = N_EDGES;
}

__global__ __launch_bounds__(256) void scatter_k(const int* __restrict__ ei,
                                                 const int* __restrict__ roff,
                                                 int* __restrict__ cursor,
                                                 int* __restrict__ ssrc) {
  int e = blockIdx.x * 256 + threadIdx.x;
  if (e >= N_EDGES) return;
  int dst = ei[N_EDGES + e];
  int pos = roff[dst] + atomicAdd(&cursor[dst], 1);
  ssrc[pos] = ei[e];
}

// ======== weight splits: W1[128][320] -> W1T[320][128] hi/lo ; W2 likewise =
__global__ __launch_bounds__(256) void conv_w(const float* __restrict__ W1,
                                              const float* __restrict__ W2,
                                              unsigned short* __restrict__ W1hT,
                                              unsigned short* __restrict__ W1lT,
                                              unsigned short* __restrict__ W2hT,
                                              unsigned short* __restrict__ W2lT) {
  int i = blockIdx.x * 256 + threadIdx.x;
  if (i < IN_CH * HC) {                 // i = n*128 + k
    int n = i >> 7, k = i & 127;
    float v = W1[(size_t)k * HC + n];
    unsigned short h = f2bf(v);
    W1hT[i] = h; W1lT[i] = f2bf(v - bf2f(h));
  } else {
    int j = i - IN_CH * HC;
    if (j < OUT_CH * HC) {              // j = c*320 + k
      int c = j / HC, k = j - c * HC;
      float v = W2[(size_t)k * OUT_CH + c];
      unsigned short h = f2bf(v);
      W2hT[j] = h; W2lT[j] = f2bf(v - bf2f(h));
    }
  }
}

// ======== GEMM1 (fused X-split) : h1b[N,320](bf16) = X @ W1 ================
// block = 64-row x 320-col strip; wave = 16 rows x 20 col-tiles.
// Reads X f32 directly, splits hi/lo bf16 in registers (conv_x fused away).
// C/D: col=lane&15, row=(lane>>4)*4+reg  [verified m89]
__global__ __launch_bounds__(256) void gemm1_mfma(const float* __restrict__ X,
                                                  const unsigned short* __restrict__ WhT,
                                                  const unsigned short* __restrict__ WlT,
                                                  unsigned short* __restrict__ Hb) {
  const int wave = threadIdx.x >> 6;
  const int lane = threadIdx.x & 63;
  const int row0 = blockIdx.x * 64 + wave * 16;
  const int r = lane & 15;
  const int kg = lane >> 4;                          // 0..3
  int arow = row0 + r; if (arow >= N_NODES) arow = N_NODES - 1;
  const float* xrow = X + (size_t)arow * IN_CH + kg * 8;
  const unsigned short* wb = WhT + (size_t)r * IN_CH + kg * 8;   // col-tile 0
  const unsigned short* lb = WlT + (size_t)r * IN_CH + kg * 8;
  f32x4 acc[20];
  #pragma unroll
  for (int c = 0; c < 20; c++) acc[c] = f32x4{0.f, 0.f, 0.f, 0.f};
  #pragma unroll
  for (int k0 = 0; k0 < IN_CH; k0 += 32) {
    float4 u = *reinterpret_cast<const float4*>(xrow + k0);
    float4 w = *reinterpret_cast<const float4*>(xrow + k0 + 4);
    float uv0 = u.x, uv1 = u.y, uv2 = u.z, uv3 = u.w;
    float uv4 = w.x, uv5 = w.y, uv6 = w.z, uv7 = w.w;
    bf16x8 ah, al;
    unsigned short hh;
    hh = f2bf(uv0); ah[0] = (short)hh; al[0] = (short)f2bf(uv0 - bf2f(hh));
    hh = f2bf(uv1); ah[1] = (short)hh; al[1] = (short)f2bf(uv1 - bf2f(hh));
    hh = f2bf(uv2); ah[2] = (short)hh; al[2] = (short)f2bf(uv2 - bf2f(hh));
    hh = f2bf(uv3); ah[3] = (short)hh; al[3] = (short)f2bf(uv3 - bf2f(hh));
    hh = f2bf(uv4); ah[4] = (short)hh; al[4] = (short)f2bf(uv4 - bf2f(hh));
    hh = f2bf(uv5); ah[5] = (short)hh; al[5] = (short)f2bf(uv5 - bf2f(hh));
    hh = f2bf(uv6); ah[6] = (short)hh; al[6] = (short)f2bf(uv6 - bf2f(hh));
    hh = f2bf(uv7); ah[7] = (short)hh; al[7] = (short)f2bf(uv7 - bf2f(hh));
    #pragma unroll
    for (int c = 0; c < 20; c++) {
      bf16x8 bh = *reinterpret_cast<const bf16x8*>(wb + (size_t)c * 16 * IN_CH + k0);
      bf16x8 bl = *reinterpret_cast<const bf16x8*>(lb + (size_t)c * 16 * IN_CH + k0);
      acc[c] = __builtin_amdgcn_mfma_f32_16x16x32_bf16(ah, bh, acc[c], 0, 0, 0);
      acc[c] = __builtin_amdgcn_mfma_f32_16x16x32_bf16(ah, bl, acc[c], 0, 0, 0);
      acc[c] = __builtin_amdgcn_mfma_f32_16x16x32_bf16(al, bh, acc[c], 0, 0, 0);
    }
  }
  const int crow0 = row0 + kg * 4;
  #pragma unroll
  for (int c = 0; c < 20; c++) {
    const int ccol = c * 16 + r;
    #pragma unroll
    for (int t = 0; t < 4; t++) {
      int rr = crow0 + t;
      if (rr < N_NODES) Hb[(size_t)rr * HC + ccol] = f2bf(acc[c][t]);
    }
  }
}

// ======== GEMM2 via MFMA split-bf16: h2[N,32](f32) = act @ W2 ==============
__global__ __launch_bounds__(256) void gemm2_mfma(const unsigned short* __restrict__ Ah,
                                                  const unsigned short* __restrict__ Al,
                                                  const unsigned short* __restrict__ WhT,
                                                  const unsigned short* __restrict__ WlT,
                                                  float* __restrict__ H) {
  const int wave = threadIdx.x >> 6;
  const int lane = threadIdx.x & 63;
  const int row0 = blockIdx.x * 64 + wave * 16;
  const int r = lane & 15;
  const int kg = lane >> 4;
  int arow = row0 + r; if (arow >= N_NODES) arow = N_NODES - 1;
  const unsigned short* ah_p = Ah + (size_t)arow * HC + kg * 8;
  const unsigned short* al_p = Al + (size_t)arow * HC + kg * 8;
  const unsigned short* wb = WhT + (size_t)r * HC + kg * 8;
  const unsigned short* lb = WlT + (size_t)r * HC + kg * 8;
  f32x4 acc[2];
  acc[0] = f32x4{0.f, 0.f, 0.f, 0.f};
  acc[1] = f32x4{0.f, 0.f, 0.f, 0.f};
  #pragma unroll
  for (int k0 = 0; k0 < HC; k0 += 32) {
    bf16x8 ah = *reinterpret_cast<const bf16x8*>(ah_p + k0);
    bf16x8 al = *reinterpret_cast<const bf16x8*>(al_p + k0);
    #pragma unroll
    for (int c = 0; c < 2; c++) {
      bf16x8 bh = *reinterpret_cast<const bf16x8*>(wb + (size_t)c * 16 * HC + k0);
      bf16x8 bl = *reinterpret_cast<const bf16x8*>(lb + (size_t)c * 16 * HC + k0);
      acc[c] = __builtin_amdgcn_mfma_f32_16x16x32_bf16(ah, bh, acc[c], 0, 0, 0);
      acc[c] = __builtin_amdgcn_mfma_f32_16x16x32_bf16(ah, bl, acc[c], 0, 0, 0);
      acc[c] = __builtin_amdgcn_mfma_f32_16x16x32_bf16(al, bh, acc[c], 0, 0, 0);
    }
  }
  const int crow0 = row0 + kg * 4;
  #pragma unroll
  for (int c = 0; c < 2; c++) {
    const int ccol = c * 16 + r;
    #pragma unroll
    for (int t = 0; t < 4; t++) {
      int rr = crow0 + t;
      if (rr < N_NODES) H[(size_t)rr * OUT_CH + ccol] = acc[c][t];
    }
  }
}

// --- e_src/e_dst per (node, head): dot(h1b[n,h,:], a_src[h,:]) (bf16 h1) ---
__global__ __launch_bounds__(256) void edot1(const unsigned short* __restrict__ h1b,
                                             const float* __restrict__ a_src,
                                             const float* __restrict__ a_dst,
                                             float* __restrict__ es,
                                             float* __restrict__ ed) {
  int idx = blockIdx.x * 256 + threadIdx.x;
  if (idx >= N_NODES * HEADS) return;
  int n = idx / HEADS, h = idx - n * HEADS;
  const uint4* hp = reinterpret_cast<const uint4*>(h1b + (size_t)n * HC + h * OUT_CH);
  const float2* ap = reinterpret_cast<const float2*>(a_src + h * OUT_CH);
  const float2* bp = reinterpret_cast<const float2*>(a_dst + h * OUT_CH);
  float s = 0.f, d = 0.f;
  #pragma unroll
  for (int q = 0; q < 4; q++) {                      // 8 bf16 per uint4
    uint4 u = hp[q];
    unsigned w[4] = {u.x, u.y, u.z, u.w};
    #pragma unroll
    for (int k = 0; k < 4; k++) {
      float lo = bflo(w[k]), hi = bfhi(w[k]);
      float2 av = ap[q * 4 + k], bv = bp[q * 4 + k];
      s += lo * av.x + hi * av.y;
      d += lo * bv.x + hi * bv.y;
    }
  }
  es[idx] = s; ed[idx] = d;
}

// ------ layer-1 aggregation: one wave per dst node ------------------------
// Phase 1: lane e owns edge e; ex[10] -> LDS (+ src byte-offset). No butterfly.
// Phase 2: 2 edges/iter; denominators accumulated IN the gather loop
//   (dm += cm, dt += ct) and merged with one shfl_xor(32) at the end.
__global__ __launch_bounds__(256) void agg1(const int* __restrict__ roff,
                                            const int* __restrict__ ssrc,
                                            const float* __restrict__ es,
                                            const float* __restrict__ ed,
                                            const unsigned short* __restrict__ h1b,
                                            const float* __restrict__ b1,
                                            unsigned short* __restrict__ acth,
                                            unsigned short* __restrict__ actl) {
  __shared__ float lds[4][64][11];   // [wave][edge][0..9]=ex, [10]=byteoff bits
  const int n = (blockIdx.x * 256 + threadIdx.x) >> 6;
  if (n >= N_NODES) return;
  const int wslot = threadIdx.x >> 6;
  const int lane = threadIdx.x & 63;
  const int beg = roff[n];
  const int deg = roff[n + 1] - beg;

  if (deg == 0) {
    #pragma unroll
    for (int q = 0; q < 5; q++) {
      float v = elu(b1[lane + 64 * q]);
      store_split(acth, actl, (size_t)n * HC + lane + 64 * q, v);
    }
    return;
  }

  if (deg <= 64) {
    // ---- phase 1 ----
    const int active = (lane < deg);
    const int src = ssrc[beg + (active ? lane : 0)];
    #pragma unroll
    for (int p = 0; p < 5; p++) {
      float2 edp = *reinterpret_cast<const float2*>(ed + n * 10 + 2 * p);
      float2 esp = *reinterpret_cast<const float2*>(es + src * 10 + 2 * p);
      lds[wslot][lane][2 * p]     = active ? expf(leaky(esp.x + edp.x)) : 0.f;
      lds[wslot][lane][2 * p + 1] = active ? expf(leaky(esp.y + edp.y)) : 0.f;
    }
    lds[wslot][lane][10] = __int_as_float(src * (HC * 2));   // byte offset

    // ---- phase 2: 2 edges/iter, uint4 main + uint tail, in-loop denoms ----
    const int half = lane >> 5;
    const int lc = lane & 31;
    const int hm = lc >> 2;            // head of main cols 8lc..8lc+7
    const int ht = 8 + (lc >> 4);      // head of tail cols 256+2lc..+1
    float accm[8] = {};
    float acct0 = 0.f, acct1 = 0.f, dm = 0.f, dt = 0.f;
    const int dege = (deg + 1) & ~1;   // edges >= deg have ex=0, valid off
    const char* basem = reinterpret_cast<const char*>(h1b + 8 * lc);
    const char* baset = reinterpret_cast<const char*>(h1b + 256 + 2 * lc);
    for (int j = 0; j < dege; j += 2) {
      const int e = j + half;
      int off = __float_as_int(lds[wslot][e][10]);
      float cm = lds[wslot][e][hm];
      float ct = lds[wslot][e][ht];
      uint4 v = *reinterpret_cast<const uint4*>(basem + off);
      unsigned t = *reinterpret_cast<const unsigned*>(baset + off);
      unsigned w0 = v.x, w1 = v.y, w2 = v.z, w3 = v.w;
      accm[0] = fmaf(bflo(w0), cm, accm[0]);
      accm[1] = fmaf(bfhi(w0), cm, accm[1]);
      accm[2] = fmaf(bflo(w1), cm, accm[2]);
      accm[3] = fmaf(bfhi(w1), cm, accm[3]);
      accm[4] = fmaf(bflo(w2), cm, accm[4]);
      accm[5] = fmaf(bfhi(w2), cm, accm[5]);
      accm[6] = fmaf(bflo(w3), cm, accm[6]);
      accm[7] = fmaf(bfhi(w3), cm, accm[7]);
      acct0 = fmaf(bflo(t), ct, acct0);
      acct1 = fmaf(bfhi(t), ct, acct1);
      dm += cm;
      dt += ct;
    }
    // merge halves
    #pragma unroll
    for (int k = 0; k < 8; k++) accm[k] += __shfl_xor(accm[k], 32);
    acct0 += __shfl_xor(acct0, 32);
    acct1 += __shfl_xor(acct1, 32);
    dm += __shfl_xor(dm, 32);
    dt += __shfl_xor(dt, 32);

    if (lane < 32) {
      const float invm = 1.f / (dm + 1e-16f);
      const size_t base = (size_t)n * HC;
      ushort4 sh0, sl0, sh1, sl1;
      float vv;
      unsigned short hh;
      vv = elu(accm[0] * invm + b1[8 * lc + 0]); hh = f2bf(vv); sh0.x = hh; sl0.x = f2bf(vv - bf2f(hh));
      vv = elu(accm[1] * invm + b1[8 * lc + 1]); hh = f2bf(vv); sh0.y = hh; sl0.y = f2bf(vv - bf2f(hh));
      vv = elu(accm[2] * invm + b1[8 * lc + 2]); hh = f2bf(vv); sh0.z = hh; sl0.z = f2bf(vv - bf2f(hh));
      vv = elu(accm[3] * invm + b1[8 * lc + 3]); hh = f2bf(vv); sh0.w = hh; sl0.w = f2bf(vv - bf2f(hh));
      vv = elu(accm[4] * invm + b1[8 * lc + 4]); hh = f2bf(vv); sh1.x = hh; sl1.x = f2bf(vv - bf2f(hh));
      vv = elu(accm[5] * invm + b1[8 * lc + 5]); hh = f2bf(vv); sh1.y = hh; sl1.y = f2bf(vv - bf2f(hh));
      vv = elu(accm[6] * invm + b1[8 * lc + 6]); hh = f2bf(vv); sh1.z = hh; sl1.z = f2bf(vv - bf2f(hh));
      vv = elu(accm[7] * invm + b1[8 * lc + 7]); hh = f2bf(vv); sh1.w = hh; sl1.w = f2bf(vv - bf2f(hh));
      *reinterpret_cast<ushort4*>(acth + base + 8 * lc) = sh0;
      *reinterpret_cast<ushort4*>(acth + base + 8 * lc + 4) = sh1;
      *reinterpret_cast<ushort4*>(actl + base + 8 * lc) = sl0;
      *reinterpret_cast<ushort4*>(actl + base + 8 * lc + 4) = sl1;
      const float invt = 1.f / (dt + 1e-16f);
      ushort2 th, tl;
      vv = elu(acct0 * invt + b1[256 + 2 * lc + 0]); hh = f2bf(vv); th.x = hh; tl.x = f2bf(vv - bf2f(hh));
      vv = elu(acct1 * invt + b1[256 + 2 * lc + 1]); hh = f2bf(vv); th.y = hh; tl.y = f2bf(vv - bf2f(hh));
      *reinterpret_cast<ushort2*>(acth + base + 256 + 2 * lc) = th;
      *reinterpret_cast<ushort2*>(actl + base + 256 + 2 * lc) = tl;
    }
  } else {
    // ---- slow fallback (deg > 64): per-lane redundant 2-pass ----
    const int hb = lane >> 5;
    float acc[5] = {};
    float edv[5], m2[5];
    #pragma unroll
    for (int q = 0; q < 5; q++) { edv[q] = ed[n * 10 + 2 * q + hb]; m2[q] = -1e30f; }
    for (int j = beg; j < beg + deg; j++) {
      int src = ssrc[j];
      #pragma unroll
      for (int q = 0; q < 5; q++)
        m2[q] = fmaxf(m2[q], leaky(es[src * 10 + 2 * q + hb] + edv[q]));
    }
    float d2[5] = {};
    for (int j = beg; j < beg + deg; j++) {
      int src = ssrc[j];
      const unsigned short* hrow = h1b + (size_t)src * HC + lane;
      #pragma unroll
      for (int q = 0; q < 5; q++) {
        float ex = expf(leaky(es[src * 10 + 2 * q + hb] + edv[q]) - m2[q]);
        acc[q] = fmaf(bf2f(hrow[64 * q]), ex, acc[q]);
        d2[q] += ex;
      }
    }
    #pragma unroll
    for (int q = 0; q < 5; q++) {
      float v = elu(acc[q] / (d2[q] + 1e-16f) + b1[lane + 64 * q]);
      store_split(acth, actl, (size_t)n * HC + lane + 64 * q, v);
    }
  }
}

// ---------------- e_src2/e_dst2 per node (H=1) -----------------------------
__global__ __launch_bounds__(256) void edot2(const float* __restrict__ h2,
                                             const float* __restrict__ a_src,
                                             const float* __restrict__ a_dst,
                                             float* __restrict__ es,
                                             float* __restrict__ ed) {
  int n = blockIdx.x * 256 + threadIdx.x;
  if (n >= N_NODES) return;
  const float4* hp = reinterpret_cast<const float4*>(h2 + (size_t)n * OUT_CH);
  const float4* ap = reinterpret_cast<const float4*>(a_src);
  const float4* bp = reinterpret_cast<const float4*>(a_dst);
  float s = 0.f, d = 0.f;
  #pragma unroll
  for (int q = 0; q < 8; q++) {
    float4 hv = hp[q], av = ap[q], dv = bp[q];
    s += hv.x * av.x + hv.y * av.y + hv.z * av.z + hv.w * av.w;
    d += hv.x * dv.x + hv.y * dv.y + hv.z * dv.z + hv.w * dv.w;
  }
  es[n] = s; ed[n] = d;
}

// ------ layer-2 aggregation: one wave per node, in-loop denom, fused pool --
__global__ __launch_bounds__(256) void agg2(const int* __restrict__ roff,
                                            const int* __restrict__ ssrc,
                                            const float* __restrict__ es,
                                            const float* __restrict__ ed,
                                            const float* __restrict__ h2,
                                            const float* __restrict__ b2,
                                            const int* __restrict__ batch,
                                            unsigned* __restrict__ pooled) {
  __shared__ float lds[4][64][2];    // [wave][edge][0]=ex, [1]=byteoff bits
  const int n = (blockIdx.x * 256 + threadIdx.x) >> 6;
  if (n >= N_NODES) return;
  const int wslot = threadIdx.x >> 6;
  const int lane = threadIdx.x & 63;
  const int c = lane & 31;
  const int hb = lane >> 5;
  const int beg = roff[n];
  const int deg = roff[n + 1] - beg;
  const int g = batch[n];

  if (deg == 0) {
    if (lane < 32) {
      float v = elu(b2[c]);
      atomicMax(&pooled[g * OUT_CH + c], fmap(v));
    }
    return;
  }

  float acc = 0.f, dacc = 0.f, dtot;

  if (deg <= 64) {
    const int active = (lane < deg);
    const int src = ssrc[beg + (active ? lane : 0)];
    const float edv = ed[n];
    float ex = active ? expf(leaky(es[src] + edv)) : 0.f;
    lds[wslot][lane][0] = ex;
    lds[wslot][lane][1] = __int_as_float(src * (OUT_CH * 4));  // byte offset
    const char* baseh = reinterpret_cast<const char*>(h2 + c);
    int j = hb;
    for (; j + 6 < deg; j += 8) {
      int o0 = __float_as_int(lds[wslot][j + 0][1]);
      int o1 = __float_as_int(lds[wslot][j + 2][1]);
      int o2 = __float_as_int(lds[wslot][j + 4][1]);
      int o3 = __float_as_int(lds[wslot][j + 6][1]);
      float c0 = lds[wslot][j + 0][0];
      float c1 = lds[wslot][j + 2][0];
      float c2 = lds[wslot][j + 4][0];
      float c3 = lds[wslot][j + 6][0];
      float v0 = *reinterpret_cast<const float*>(baseh + o0);
      float v1 = *reinterpret_cast<const float*>(baseh + o1);
      float v2 = *reinterpret_cast<const float*>(baseh + o2);
      float v3 = *reinterpret_cast<const float*>(baseh + o3);
      acc = fmaf(v0, c0, acc);
      acc = fmaf(v1, c1, acc);
      acc = fmaf(v2, c2, acc);
      acc = fmaf(v3, c3, acc);
      dacc += c0 + c1 + c2 + c3;
    }
    for (; j < deg; j += 2) {
      int oj = __float_as_int(lds[wslot][j][1]);
      float cj = lds[wslot][j][0];
      acc = fmaf(*reinterpret_cast<const float*>(baseh + oj), cj, acc);
      dacc += cj;
    }
    acc += __shfl_xor(acc, 32);
    dacc += __shfl_xor(dacc, 32);
    dtot = dacc;
  } else {
    const float edv = ed[n];
    float m = -1e30f;
    for (int j = beg; j < beg + deg; j++)
      m = fmaxf(m, leaky(es[ssrc[j]] + edv));
    float d = 0.f;
    for (int j = beg + hb; j < beg + deg; j += 2) {
      int src = ssrc[j];
      float ex = expf(leaky(es[src] + edv) - m);
      acc = fmaf(h2[(size_t)src * OUT_CH + c], ex, acc);
      d += ex;
    }
    acc += __shfl_xor(acc, 32);
    d += __shfl_xor(d, 32);
    dtot = d;
  }

  if (lane < 32) {
    float v = elu(acc / (dtot + 1e-16f) + b2[c]);
    atomicMax(&pooled[g * OUT_CH + c], fmap(v));
  }
}

// -------- final: out[g,c] = relu(pooled[g,:] @ fc_w[:,c] + fc_b[c]) --------
__global__ __launch_bounds__(256) void final_k(const unsigned* __restrict__ pooled,
                                               const float* __restrict__ fc_w,
                                               const float* __restrict__ fc_b,
                                               float* __restrict__ out) {
  int idx = blockIdx.x * 256 + threadIdx.x;
  if (idx >= N_GRAPHS * OUT_CH) return;
  int g = idx >> 5, c = idx & 31;
  float s = fc_b[c];
  #pragma unroll
  for (int k = 0; k < OUT_CH; k++) {
    unsigned u = pooled[g * OUT_CH + k];
    float p = (u == 0u) ? 0.f : funmap(u);
    s += p * fc_w[k * OUT_CH + c];
  }
  out[idx] = s > 0.f ? s : 0.f;
}

extern "C" void kernel_launch(void* const* d_in, const int* in_sizes, int n_in,
                              void* d_out, int out_size, void* d_ws, size_t ws_size,
                              hipStream_t stream) {
  const float* x      = (const float*)d_in[0];
  const int*   ei     = (const int*)d_in[1];
  const int*   batch  = (const int*)d_in[2];
  const float* W1     = (const float*)d_in[4];
  const float* a_src1 = (const float*)d_in[5];
  const float* a_dst1 = (const float*)d_in[6];
  const float* b1     = (const float*)d_in[7];
  const float* W2     = (const float*)d_in[8];
  const float* a_src2 = (const float*)d_in[9];
  const float* a_dst2 = (const float*)d_in[10];
  const float* b2     = (const float*)d_in[11];
  const float* fc_w   = (const float*)d_in[12];
  const float* fc_b   = (const float*)d_in[13];
  float* out = (float*)d_out;

  // ---- workspace layout (<= 136 MB, phase-aliased) ----
  // A [0,64M):   h1b bf16 32MB (gemm1->edot1->agg1); h2 f32 reuses after agg1
  // B [64M,128M): act_h|act_l (64M, written by agg1)
  // S [128M,136M): CSR + es/ed + pooled; W-splits alias dead deg/cursor
  char* ws = (char*)d_ws;
  unsigned short* h1b = (unsigned short*)(ws);              // 32 MB
  float* h2   = (float*)(ws);                               // after agg1
  unsigned short* acth = (unsigned short*)(ws + 64000000);  // 32 MB
  unsigned short* actl = (unsigned short*)(ws + 96000000);  // 32 MB
  char*  S    = ws + 128000000;
  int*   ssrc   = (int*)(S);                  // 3.2 MB
  int*   roff   = (int*)(S + 3200000);        // 200,004 B
  int*   deg    = (int*)(S + 3400064);        // 200,000 B (dead after scan)
  int*   cursor = (int*)(S + 3600064);        // 200,000 B (dead after scatter)
  unsigned short* W1hT = (unsigned short*)(S + 3400064);            // 81,920 B
  unsigned short* W1lT = (unsigned short*)(S + 3400064 + 81920);    // 81,920 B
  unsigned short* W2hT = (unsigned short*)(S + 3400064 + 163840);   // 20,480 B
  unsigned short* W2lT = (unsigned short*)(S + 3400064 + 184320);   // 20,480 B
  float* es1    = (float*)(S + 3800064);      // 2 MB
  float* ed1    = (float*)(S + 5800064);      // 2 MB
  int*   bsum   = (int*)(S + 7800064);        // 784 B
  unsigned* pooled = (unsigned*)(S + 7801600);// 64 KB
  float* es2 = es1; float* ed2 = ed1;         // dead after agg1

  // ---- CSR build ----
  hipMemsetAsync(deg, 0, (size_t)N_NODES * 4, stream);
  hipMemsetAsync(cursor, 0, (size_t)N_NODES * 4, stream);
  hist_k   <<<(N_EDGES + 255) / 256, 256, 0, stream>>>(ei, deg);
  scan_blk <<<NBLK_SCAN, 256, 0, stream>>>(deg, roff, bsum);
  scan_top <<<1, 256, 0, stream>>>(bsum);
  scan_add <<<NBLK_SCAN, 256, 0, stream>>>(roff, bsum);
  scatter_k<<<(N_EDGES + 255) / 256, 256, 0, stream>>>(ei, roff, cursor, ssrc);

  // ---- weight splits (AFTER scatter: aliases dead deg/cursor) ----
  conv_w<<<(IN_CH * HC + OUT_CH * HC + 255) / 256, 256, 0, stream>>>(
      W1, W2, W1hT, W1lT, W2hT, W2lT);

  // ---- layer 1 ----
  gemm1_mfma<<<(N_NODES + 63) / 64, 256, 0, stream>>>(x, W1hT, W1lT, h1b);
  edot1<<<(N_NODES * HEADS + 255) / 256, 256, 0, stream>>>(h1b, a_src1, a_dst1, es1, ed1);
  agg1 <<<(N_NODES * 64 + 255) / 256, 256, 0, stream>>>(roff, ssrc, es1, ed1, h1b, b1,
                                                        acth, actl);

  // ---- layer 2 ----
  hipMemsetAsync(pooled, 0, (size_t)N_GRAPHS * OUT_CH * 4, stream);
  gemm2_mfma<<<(N_NODES + 63) / 64, 256, 0, stream>>>(acth, actl, W2hT, W2lT, h2);
  edot2<<<(N_NODES + 255) / 256, 256, 0, stream>>>(h2, a_src2, a_dst2, es2, ed2);
  agg2 <<<(N_NODES * 64 + 255) / 256, 256, 0, stream>>>(roff, ssrc, es2, ed2, h2, b2,
                                                        batch, pooled);
  final_k<<<(N_GRAPHS * OUT_CH + 255) / 256, 256, 0, stream>>>(pooled, fc_w, fc_b, out);
}